// Round 8
// baseline (240.272 us; speedup 1.0000x reference)
//
#include <hip/hip_runtime.h>
#include <hip/hip_bf16.h>
#include <math.h>

#define BB 4
#define CC 64
#define HH 128
#define WW 128
#define HW (HH*WW)          // 16384
#define NPIX (BB*HW)        // 65536

typedef __attribute__((ext_vector_type(8))) short short8;   // 8 bf16
typedef __attribute__((ext_vector_type(4))) float f32x4;

__device__ __forceinline__ float bf2f(ushort u) {
  union { unsigned u; float f; } v; v.u = ((unsigned)u) << 16; return v.f;
}
__device__ __forceinline__ ushort f2bf(float f) {
  __hip_bfloat16 h = __float2bfloat16(f); return *(ushort*)&h;
}

// ---------------------------------------------------------------------------
// Prep (verified, unchanged): NCHW fp32 -> channels-last bf16 + weights.
// ---------------------------------------------------------------------------
__global__ __launch_bounds__(256) void k_prep(
    const float* __restrict__ x, const float* __restrict__ inter,
    const float* __restrict__ w_off, const float* __restrict__ w_dcn,
    const float* __restrict__ wg1, const float* __restrict__ wb1,
    const float* __restrict__ wg2, const float* __restrict__ wb2,
    ushort* __restrict__ x_clh, ushort* __restrict__ inter_clh,
    ushort* __restrict__ wfb, ushort* __restrict__ wdT,
    ushort* __restrict__ w1gb, ushort* __restrict__ w1bb,
    ushort* __restrict__ w2gb, ushort* __restrict__ w2bb,
    float* __restrict__ zp) {
  __shared__ __align__(16) float tile[64 * 128];   // 32 KiB, xor-swizzled
  int blk = blockIdx.x;
  int tid = threadIdx.x;
  if (blk < 1024) {
    int sel = blk >> 9;
    int bh = blk & 511;
    int b = bh >> 7, h = bh & 127;
    const float* src = sel ? inter : x;
    ushort* dst = sel ? inter_clh : x_clh;
    const float* sp = src + (size_t)(b * 64) * HW + h * WW;
#pragma unroll
    for (int it = 0; it < 8; ++it) {
      int idx = it * 256 + tid;
      int c = idx >> 5, wq = idx & 31;
      float4 v = *(const float4*)(sp + (size_t)c * HW + wq * 4);
      int s = (c >> 3) & 7;
      *(float4*)(&tile[c * 128 + ((wq ^ s) << 2)]) = v;
    }
    __syncthreads();
    ushort* dp = dst + ((size_t)b * HW + h * WW) * 64;
#pragma unroll
    for (int it = 0; it < 4; ++it) {
      int idx = it * 256 + tid;
      int w = idx >> 3, c8 = idx & 7;
      short8 outv;
#pragma unroll
      for (int j = 0; j < 8; ++j) {
        int c = c8 * 8 + j;
        int sl = (w >> 2) ^ c8;
        float f = tile[c * 128 + (sl << 2) + (w & 3)];
        outv[j] = (short)f2bf(f);
      }
      *(short8*)(dp + (size_t)w * 64 + c8 * 8) = outv;
    }
  } else if (blk < 1168) {
    int i = (blk - 1024) * 256 + tid;
    if (i < 64) zp[i] = 0.f;
    if (i < 9 * 32 * 128) {
      int tap = i >> 12, rem = i & 4095, m = rem >> 7, c = rem & 127;
      float v = (m < 27) ? w_off[(size_t)(m * 128 + c) * 9 + tap] : 0.f;
      wfb[i] = f2bf(v);
    }
  } else if (blk < 1312) {
    int i = (blk - 1168) * 256 + tid;
    if (i < 64 * 64 * 9) {
      int o = i / 576, rem = i % 576, k = rem >> 6, c = rem & 63;
      wdT[i] = f2bf(w_dcn[(o * 64 + c) * 9 + k]);
    }
  } else {
    int i = (blk - 1312) * 256 + tid;   // 0..16383
    int m = i >> 12, j = i & 4095;
    const float* src = (m == 0) ? wg1 : (m == 1) ? wb1 : (m == 2) ? wg2 : wb2;
    ushort* dst = (m == 0) ? w1gb : (m == 1) ? w1bb : (m == 2) ? w2gb : w2bb;
    dst[j] = f2bf(src[j]);
  }
}

// ---------------------------------------------------------------------------
// OMEGA v8: round-7 phases 1/2/5 verbatim; phases 3/4/6/7 remapped to
// wave = (pt = px-half, o-range = mt*32 + og*16) so that phase 6 (DCN)
// becomes BARRIER-FREE: each lane's MFMA B-fragment (pixel = its col,
// tap t, channels kk*32+quad*8) is its own bilinear gather, built in
// registers and fed straight to MFMA. Removes 6 of 8 barriers (each
// barrier drains vmcnt/lgkm — round-6-proven mechanism), the S LDS
// round-trip, and its bank conflicts. Price: px-half gather/bilerp is
// duplicated across the 2 o-half waves (2x gather loads, L2-absorbed).
// 5 barriers total. No launch_bounds clamp (spill tripwire=WRITE_SIZE).
// LDS alias map (bytes in BIGB, 29376 B):
//   [0,29376)      phase 1-2: conv halo (204 rows x 72 shorts)
//   [12800,18560)  phase 5-6: coords (5 x 288 x 4 B)
//   [12800,22016)  phase 3-4: Sg/Sb (2 x 32 x 72 shorts)
//   [22016,25712)  phase 3-5: om_local (27 x 33 f32)
// ---------------------------------------------------------------------------
#define CPITCH 72    // shorts per (srcrow, px) channel row in conv halo
#define NPX 32       // pixels per block
#define FPX 72       // shorts per px row in Sg/Sb

__global__ __launch_bounds__(256) void k_omega(
    const float* __restrict__ x, const ushort* __restrict__ x_clh,
    const ushort* __restrict__ inter_clh,
    const float* __restrict__ b_off, const ushort* __restrict__ wfb,
    const ushort* __restrict__ wdT,
    const ushort* __restrict__ w1gb, const ushort* __restrict__ w1bb,
    const ushort* __restrict__ w2gb, const ushort* __restrict__ w2bb,
    const ushort* __restrict__ zp16, float* __restrict__ out) {
  __shared__ __align__(16) ushort BIGB[6 * 34 * CPITCH];   // 29376 B total LDS
  ushort* Sg = BIGB + 6400;               // 32*72 shorts (phases 3-4)
  ushort* Sb = Sg + NPX * FPX;            // ends at short 11008 = byte 22016
  int*   cy  = (int*)(BIGB + 6400);       // coords (phases 5-6): 288 each
  int*   cx  = cy + 288;
  float* cwy = (float*)(cx + 288);
  float* cwx = cwy + 288;
  float* cm  = cwx + 288;                 // 5760 B total, ends byte 18560
  float* oml = (float*)(BIGB + 11008);    // om_local 27x33 f32 @ byte 22016

  int tid = threadIdx.x;
  int wave = tid >> 6, lane = tid & 63;
  int quad = lane >> 4, col = lane & 15;
  // XCD-chunked swizzle (r7: FETCH -36%, kept).
  int bid = blockIdx.x;
  int wid = (bid & 7) * 256 + (bid >> 3);
  int pg0 = wid * NPX;
  int b = pg0 >> 14, hw0 = pg0 & 16383;
  int h = hw0 >> 7, w0 = hw0 & 127;
  int pt = wave >> 1, mt = wave & 1;
  int ob = __builtin_amdgcn_readfirstlane(mt * 32);   // SFT/DCN o-base
  int mypx = pt * 16 + col;                           // lane's pixel (local)

  // ---- phase 1: conv halo staging (verbatim) ----
  {
    int ch = (tid & 7) * 8;
    unsigned bbase = (unsigned)b * HW;
#pragma unroll
    for (int it = 0; it < 7; ++it) {
      int e = it * 32 + (tid >> 3);
      if (e < 204) {
        int srcrow = e / 34, pxl = e % 34;
        int src = srcrow / 3, row = srcrow % 3;
        int hs = h + row - 1;
        int ps = w0 + pxl - 1;
        bool ok = ((unsigned)hs < 128u) && ((unsigned)ps < 128u);
        int hc = hs < 0 ? 0 : (hs > 127 ? 127 : hs);
        int pc = ps < 0 ? 0 : (ps > 127 ? 127 : ps);
        const ushort* sb = src ? inter_clh : x_clh;
        short8 v = *(const short8*)(sb + ((size_t)(bbase + (hc << 7) + pc)) * 64 + ch);
        short8 z = {0, 0, 0, 0, 0, 0, 0, 0};
        if (!ok) v = z;
        *(short8*)(&BIGB[e * CPITCH + ch]) = v;
      }
    }
  }
  __syncthreads();   // B0

  // ---- phase 2: conv MFMAs (verbatim; oml store deferred past barrier) ----
  f32x4 accx = {0.f, 0.f, 0.f, 0.f}, acci = {0.f, 0.f, 0.f, 0.f};
  {
    const ushort* wb0 = wfb + (size_t)(mt * 16 + col) * 128 + quad * 8;
    int pxb = pt * 16 + col;
#pragma unroll
    for (int ky = 0; ky < 3; ++ky) {
#pragma unroll
      for (int kx = 0; kx < 3; ++kx) {
        int tap = ky * 3 + kx;
        const ushort* wt = wb0 + (size_t)tap * 4096;
#pragma unroll
        for (int ks = 0; ks < 2; ++ks) {
          short8 a0 = *(const short8*)(wt + ks * 32);
          short8 b0 = *(const short8*)(&BIGB[(ky * 34 + pxb + kx) * CPITCH + ks * 32 + quad * 8]);
          accx = __builtin_amdgcn_mfma_f32_16x16x32_bf16(a0, b0, accx, 0, 0, 0);
          short8 a1 = *(const short8*)(wt + 64 + ks * 32);
          short8 b1 = *(const short8*)(&BIGB[((3 + ky) * 34 + pxb + kx) * CPITCH + ks * 32 + quad * 8]);
          acci = __builtin_amdgcn_mfma_f32_16x16x32_bf16(a1, b1, acci, 0, 0, 0);
        }
      }
    }
  }
  __syncthreads();   // B1: halo dead; BIGB free for aliases

  // oml store into BIGB tail (disjoint from Sg/Sb written in phase 3).
#pragma unroll
  for (int r = 0; r < 4; ++r) {
    int o = mt * 16 + quad * 4 + r;
    if (o < 27) oml[o * 33 + pt * 16 + col] = accx[r] + acci[r];
  }

  // ---- phase 3: SFT stage A, (pt, ob) mapping: my 16 px x o [ob,ob+32) ----
  f32x4 ag[2], ab[2];
#pragma unroll
  for (int og = 0; og < 2; ++og) {
    ag[og] = (f32x4){0.f, 0.f, 0.f, 0.f};
    ab[og] = (f32x4){0.f, 0.f, 0.f, 0.f};
  }
#pragma unroll
  for (int ks = 0; ks < 2; ++ks) {
    short8 bf = *(const short8*)(inter_clh + (size_t)(pg0 + mypx) * 64 + ks * 32 + quad * 8);
#pragma unroll
    for (int og = 0; og < 2; ++og) {
      short8 a_g = *(const short8*)(w1gb + (size_t)(ob + og * 16 + col) * 64 + ks * 32 + quad * 8);
      short8 a_b = *(const short8*)(w1bb + (size_t)(ob + og * 16 + col) * 64 + ks * 32 + quad * 8);
      ag[og] = __builtin_amdgcn_mfma_f32_16x16x32_bf16(a_g, bf, ag[og], 0, 0, 0);
      ab[og] = __builtin_amdgcn_mfma_f32_16x16x32_bf16(a_b, bf, ab[og], 0, 0, 0);
    }
  }
#pragma unroll
  for (int og = 0; og < 2; ++og) {
    ushort pkg[4], pkb[4];
#pragma unroll
    for (int r = 0; r < 4; ++r) {
      float vg = ag[og][r]; vg = vg >= 0.f ? vg : 0.1f * vg;
      float vb = ab[og][r]; vb = vb >= 0.f ? vb : 0.1f * vb;
      pkg[r] = f2bf(vg); pkb[r] = f2bf(vb);
    }
    *(uint2*)(&Sg[mypx * FPX + ob + og * 16 + quad * 4]) = *(uint2*)pkg;
    *(uint2*)(&Sb[mypx * FPX + ob + og * 16 + quad * 4]) = *(uint2*)pkb;
  }
  __syncthreads();   // B2: oml + Sg/Sb visible

  // ---- phase 4: SFT stage B -> ev[2][4] = x + x*gamma + beta ----
  f32x4 gg[2], gb[2];
#pragma unroll
  for (int og = 0; og < 2; ++og) {
    gg[og] = (f32x4){0.f, 0.f, 0.f, 0.f};
    gb[og] = (f32x4){0.f, 0.f, 0.f, 0.f};
  }
#pragma unroll
  for (int ks = 0; ks < 2; ++ks) {
    short8 bgf = *(const short8*)(Sg + mypx * FPX + ks * 32 + quad * 8);
    short8 bbf = *(const short8*)(Sb + mypx * FPX + ks * 32 + quad * 8);
#pragma unroll
    for (int og = 0; og < 2; ++og) {
      short8 a_g = *(const short8*)(w2gb + (size_t)(ob + og * 16 + col) * 64 + ks * 32 + quad * 8);
      short8 a_b = *(const short8*)(w2bb + (size_t)(ob + og * 16 + col) * 64 + ks * 32 + quad * 8);
      gg[og] = __builtin_amdgcn_mfma_f32_16x16x32_bf16(a_g, bgf, gg[og], 0, 0, 0);
      gb[og] = __builtin_amdgcn_mfma_f32_16x16x32_bf16(a_b, bbf, gb[og], 0, 0, 0);
    }
  }
  float ev[2][4];
#pragma unroll
  for (int og = 0; og < 2; ++og)
#pragma unroll
    for (int r = 0; r < 4; ++r) {
      int o = ob + og * 16 + quad * 4 + r;
      float xv = x[(size_t)(b * 64 + o) * HW + hw0 + mypx];
      ev[og][r] = xv + xv * gg[og][r] + gb[og][r];
    }
  __syncthreads();   // B3: Sg/Sb dead; region becomes coords

  // ---- phase 5: coords once per (pixel, tap) from om_local (verbatim) ----
  for (int i = tid; i < 9 * NPX; i += 256) {
    int k = i >> 5, p = i & 31;
    float dy = oml[k * 33 + p] + b_off[k];
    float dx = oml[(9 + k) * 33 + p] + b_off[9 + k];
    float mz = oml[(18 + k) * 33 + p] + b_off[18 + k];
    float py = (float)(h + (k / 3) - 1) + dy;
    float px = (float)(w0 + p + (k % 3) - 1) + dx;
    float y0f = floorf(py), x0f = floorf(px);
    cy[i] = (int)y0f;
    cx[i] = (int)x0f;
    cwy[i] = py - y0f;
    cwx[i] = px - x0f;
    cm[i] = 1.f / (1.f + __expf(-mz));
  }
  __syncthreads();   // B4: coords ready. NO MORE BARRIERS.

  // ---- phase 6: DCN, barrier-free: per-lane register gather -> MFMA ----
  // Lane (quad,col) of wave (pt,mt): B-frag for (px = pt*16+col, tap t,
  // ch kk*32+quad*8) is its own bilinear gather. acc[og] accumulates
  // o = ob + og*16 + quad*4 + r over all 9 taps x 2 kk.
  f32x4 acc[2];
  acc[0] = (f32x4){0.f, 0.f, 0.f, 0.f};
  acc[1] = (f32x4){0.f, 0.f, 0.f, 0.f};

  const ushort* bp  = x_clh + (size_t)b * HW * 64 + quad * 8;
  const ushort* zpq = zp16 + quad * 8;
  const ushort* wd0 = wdT + (size_t)(ob + col) * 576 + quad * 8;
  const ushort* wd1 = wd0 + (size_t)16 * 576;

#pragma unroll 3
  for (int t = 0; t < 9; ++t) {
    int idx = t * NPX + mypx;
    int y0 = cy[idx], x0 = cx[idx];
    float wy = cwy[idx], wx = cwx[idx], m = cm[idx];
    bool yok0 = (unsigned)y0 < 128u, yok1 = (unsigned)(y0 + 1) < 128u;
    bool xok0 = (unsigned)x0 < 128u, xok1 = (unsigned)(x0 + 1) < 128u;
    const ushort* r0 = bp + (long long)(int)((y0 << 7) + x0) * 64;
    const ushort* r1 = r0 + (size_t)WW * 64;
    const ushort* p00 = (yok0 && xok0) ? r0 : zpq;
    const ushort* p01 = (yok0 && xok1) ? (r0 + 64) : zpq;
    const ushort* p10 = (yok1 && xok0) ? r1 : zpq;
    const ushort* p11 = (yok1 && xok1) ? (r1 + 64) : zpq;
#pragma unroll
    for (int kk = 0; kk < 2; ++kk) {
      int off = kk * 32;
      short8 s00 = *(const short8*)(p00 + off);
      short8 s01 = *(const short8*)(p01 + off);
      short8 s10 = *(const short8*)(p10 + off);
      short8 s11 = *(const short8*)(p11 + off);
      short8 bfr;
#pragma unroll
      for (int j = 0; j < 8; ++j) {
        float v00 = bf2f((ushort)s00[j]), v01 = bf2f((ushort)s01[j]);
        float v10 = bf2f((ushort)s10[j]), v11 = bf2f((ushort)s11[j]);
        float top = v00 + (v01 - v00) * wx;
        float bot = v10 + (v11 - v10) * wx;
        float val = top + (bot - top) * wy;
        bfr[j] = (short)f2bf(val * m);
      }
      short8 a0 = *(const short8*)(wd0 + t * 64 + off);
      short8 a1 = *(const short8*)(wd1 + t * 64 + off);
      acc[0] = __builtin_amdgcn_mfma_f32_16x16x32_bf16(a0, bfr, acc[0], 0, 0, 0);
      acc[1] = __builtin_amdgcn_mfma_f32_16x16x32_bf16(a1, bfr, acc[1], 0, 0, 0);
    }
  }

  // ---- phase 7: epilogue: out = ev + dcn (single pure write) ----
#pragma unroll
  for (int og = 0; og < 2; ++og)
#pragma unroll
    for (int r = 0; r < 4; ++r) {
      int o = ob + og * 16 + quad * 4 + r;
      size_t idx = (size_t)(b * 64 + o) * HW + hw0 + mypx;
      out[idx] = ev[og][r] + acc[og][r];
    }
}

// ---------------------------------------------------------------------------
// Workspace plan (float slots), compacted ~17 MB (r4-verified):
//   x_clh     ushort [0        .. 2097152)
//   inter_clh ushort [2097152  .. 4194304)
//   wfb       ushort [4194304  .. 4212736)
//   wdT       ushort [4212736  .. 4231168)
//   w1gb/w1bb/w2gb/w2bb ushort 4 x 2048 float slots [4231168 .. 4239360)
//   zp        fp32   [4239360  .. 4239424)
// ---------------------------------------------------------------------------
extern "C" void kernel_launch(void* const* d_in, const int* in_sizes, int n_in,
                              void* d_out, int out_size, void* d_ws, size_t ws_size,
                              hipStream_t stream) {
  const float* x     = (const float*)d_in[0];
  const float* inter = (const float*)d_in[1];
  const float* w_off = (const float*)d_in[2];
  const float* b_off = (const float*)d_in[3];
  const float* w_dcn = (const float*)d_in[4];
  const float* wg1   = (const float*)d_in[5];
  const float* wg2   = (const float*)d_in[6];
  const float* wb1   = (const float*)d_in[7];
  const float* wb2   = (const float*)d_in[8];
  float* out = (float*)d_out;

  float* ws        = (float*)d_ws;
  ushort* x_clh    = (ushort*)ws;
  ushort* inter_clh= (ushort*)(ws + 2097152);
  ushort* wfb      = (ushort*)(ws + 4194304);
  ushort* wdT      = (ushort*)(ws + 4212736);
  ushort* w1gb     = (ushort*)(ws + 4231168);
  ushort* w1bb     = (ushort*)(ws + 4233216);
  ushort* w2gb     = (ushort*)(ws + 4235264);
  ushort* w2bb     = (ushort*)(ws + 4237312);
  float* zp        = ws + 4239360;

  // Prep: channels-last bf16 inputs + all packed weights + zero page.
  k_prep<<<1376, 256, 0, stream>>>(x, inter, w_off, w_dcn, wg1, wb1, wg2, wb2,
                                   x_clh, inter_clh, wfb, wdT,
                                   w1gb, w1bb, w2gb, w2bb, zp);

  // Fully fused conv + SFT + DCN (v8: barrier-free register-gather DCN).
  k_omega<<<2048, 256, 0, stream>>>(x, x_clh, inter_clh, b_off, wfb, wdT,
                                    w1gb, w1bb, w2gb, w2bb,
                                    (const ushort*)zp, out);
}

// Round 9
// 172.518 us; speedup vs baseline: 1.3927x; 1.3927x over previous
//
#include <hip/hip_runtime.h>
#include <hip/hip_bf16.h>
#include <math.h>

#define BB 4
#define CC 64
#define HH 128
#define WW 128
#define HW (HH*WW)          // 16384
#define NPIX (BB*HW)        // 65536

typedef __attribute__((ext_vector_type(8))) short short8;   // 8 bf16
typedef __attribute__((ext_vector_type(4))) float f32x4;

__device__ __forceinline__ float bf2f(ushort u) {
  union { unsigned u; float f; } v; v.u = ((unsigned)u) << 16; return v.f;
}
__device__ __forceinline__ ushort f2bf(float f) {
  __hip_bfloat16 h = __float2bfloat16(f); return *(ushort*)&h;
}

// Raw barrier with LDS-only drain: does NOT force vmcnt(0), so global loads
// stay in flight across it (the round-6-proven __syncthreads drain was the
// stall). All k_omega cross-wave deps are LDS-only (audited per-barrier).
#define LGKM_BAR() do { \
  asm volatile("s_waitcnt lgkmcnt(0)" ::: "memory"); \
  __builtin_amdgcn_s_barrier(); \
} while (0)

// ---------------------------------------------------------------------------
// Prep (verified, unchanged): NCHW fp32 -> channels-last bf16 + weights.
// ---------------------------------------------------------------------------
__global__ __launch_bounds__(256) void k_prep(
    const float* __restrict__ x, const float* __restrict__ inter,
    const float* __restrict__ w_off, const float* __restrict__ w_dcn,
    const float* __restrict__ wg1, const float* __restrict__ wb1,
    const float* __restrict__ wg2, const float* __restrict__ wb2,
    ushort* __restrict__ x_clh, ushort* __restrict__ inter_clh,
    ushort* __restrict__ wfb, ushort* __restrict__ wdT,
    ushort* __restrict__ w1gb, ushort* __restrict__ w1bb,
    ushort* __restrict__ w2gb, ushort* __restrict__ w2bb,
    float* __restrict__ zp) {
  __shared__ __align__(16) float tile[64 * 128];   // 32 KiB, xor-swizzled
  int blk = blockIdx.x;
  int tid = threadIdx.x;
  if (blk < 1024) {
    int sel = blk >> 9;
    int bh = blk & 511;
    int b = bh >> 7, h = bh & 127;
    const float* src = sel ? inter : x;
    ushort* dst = sel ? inter_clh : x_clh;
    const float* sp = src + (size_t)(b * 64) * HW + h * WW;
#pragma unroll
    for (int it = 0; it < 8; ++it) {
      int idx = it * 256 + tid;
      int c = idx >> 5, wq = idx & 31;
      float4 v = *(const float4*)(sp + (size_t)c * HW + wq * 4);
      int s = (c >> 3) & 7;
      *(float4*)(&tile[c * 128 + ((wq ^ s) << 2)]) = v;
    }
    __syncthreads();
    ushort* dp = dst + ((size_t)b * HW + h * WW) * 64;
#pragma unroll
    for (int it = 0; it < 4; ++it) {
      int idx = it * 256 + tid;
      int w = idx >> 3, c8 = idx & 7;
      short8 outv;
#pragma unroll
      for (int j = 0; j < 8; ++j) {
        int c = c8 * 8 + j;
        int sl = (w >> 2) ^ c8;
        float f = tile[c * 128 + (sl << 2) + (w & 3)];
        outv[j] = (short)f2bf(f);
      }
      *(short8*)(dp + (size_t)w * 64 + c8 * 8) = outv;
    }
  } else if (blk < 1168) {
    int i = (blk - 1024) * 256 + tid;
    if (i < 64) zp[i] = 0.f;
    if (i < 9 * 32 * 128) {
      int tap = i >> 12, rem = i & 4095, m = rem >> 7, c = rem & 127;
      float v = (m < 27) ? w_off[(size_t)(m * 128 + c) * 9 + tap] : 0.f;
      wfb[i] = f2bf(v);
    }
  } else if (blk < 1312) {
    int i = (blk - 1168) * 256 + tid;
    if (i < 64 * 64 * 9) {
      int o = i / 576, rem = i % 576, k = rem >> 6, c = rem & 63;
      wdT[i] = f2bf(w_dcn[(o * 64 + c) * 9 + k]);
    }
  } else {
    int i = (blk - 1312) * 256 + tid;   // 0..16383
    int m = i >> 12, j = i & 4095;
    const float* src = (m == 0) ? wg1 : (m == 1) ? wb1 : (m == 2) ? wg2 : wb2;
    ushort* dst = (m == 0) ? w1gb : (m == 1) ? w1bb : (m == 2) ? w2gb : w2bb;
    dst[j] = f2bf(src[j]);
  }
}

// ---------------------------------------------------------------------------
// OMEGA v9 = round-7 kernel (co-best, 84 us) with:
//  (a) ALL __syncthreads -> LGKM_BAR (lgkmcnt-only drain). Every barrier's
//      cross-wave dependency is LDS-only; vmcnt draining was pure stall.
//  (b) phase-6 corner-bank prefetch (round-6 code, numerically verified):
//      chunk k+1's 12 gather loads issue BEFORE chunk k's S-ready barrier
//      and now legally complete under barrier+MFMA+barrier (no vmcnt drain).
//  (c) xv epilogue loads float across the remaining barriers for free.
// Structure, LDS map, swizzle identical to round-7. No launch_bounds clamp
// (spill tripwire = WRITE_SIZE must stay 16384 KB).
// LDS alias map (bytes in BIGB, 29376 B):
//   [0,29376)      phase 1-2: conv halo (204 rows x 72 shorts)
//   [0,12800)      phase 6:   S gather buffer (32 px x 200 shorts)
//   [12800,22016)  phase 3-4: Sg/Sb (2 x 32 x 72 shorts)
//   [12800,18560)  phase 5-6: coords (5 x 288 x 4 B)
//   [22016,25712)  phase 3-6: om_local (27 x 33 f32, written after halo dies)
// ---------------------------------------------------------------------------
#define CPITCH 72    // shorts per (srcrow, px) channel row in conv halo
#define SPITCH 200   // shorts per pixel row in gather buffer S
#define NPX 32       // pixels per block
#define FPX 72       // shorts per px row in Sg/Sb

__global__ __launch_bounds__(256) void k_omega(
    const float* __restrict__ x, const ushort* __restrict__ x_clh,
    const ushort* __restrict__ inter_clh,
    const float* __restrict__ b_off, const ushort* __restrict__ wfb,
    const ushort* __restrict__ wdT,
    const ushort* __restrict__ w1gb, const ushort* __restrict__ w1bb,
    const ushort* __restrict__ w2gb, const ushort* __restrict__ w2bb,
    const ushort* __restrict__ zp16, float* __restrict__ out) {
  __shared__ __align__(16) ushort BIGB[6 * 34 * CPITCH];   // 29376 B total LDS
  ushort* S  = BIGB;                      // 32*200 shorts = 12800 B (phases 1,6)
  ushort* Sg = BIGB + 6400;               // 32*72 shorts (phases 3-4)
  ushort* Sb = Sg + NPX * FPX;            // ends at short 11008 = byte 22016
  int*   cy  = (int*)(BIGB + 6400);       // coords (phases 5-6): 288 each
  int*   cx  = cy + 288;
  float* cwy = (float*)(cx + 288);
  float* cwx = cwy + 288;
  float* cm  = cwx + 288;                 // 5760 B total, ends byte 18560
  float* oml = (float*)(BIGB + 11008);    // om_local 27x33 f32 @ byte 22016

  int tid = threadIdx.x;
  int wave = tid >> 6, lane = tid & 63;
  int quad = lane >> 4, col = lane & 15;
  int rr = lane >> 3, g = lane & 7;
  // XCD-chunked swizzle (r7: FETCH -36%, kept).
  int bid = blockIdx.x;
  int wid = (bid & 7) * 256 + (bid >> 3);
  int pg0 = wid * NPX;
  int b = pg0 >> 14, hw0 = pg0 & 16383;
  int h = hw0 >> 7, w0 = hw0 & 127;
  int pt = wave >> 1, mt = wave & 1;
  int o_base = __builtin_amdgcn_readfirstlane(wave * 16);

  // ---- phase 1: conv halo staging ----
  {
    int ch = (tid & 7) * 8;
    unsigned bbase = (unsigned)b * HW;
#pragma unroll
    for (int it = 0; it < 7; ++it) {
      int e = it * 32 + (tid >> 3);
      if (e < 204) {
        int srcrow = e / 34, pxl = e % 34;
        int src = srcrow / 3, row = srcrow % 3;
        int hs = h + row - 1;
        int ps = w0 + pxl - 1;
        bool ok = ((unsigned)hs < 128u) && ((unsigned)ps < 128u);
        int hc = hs < 0 ? 0 : (hs > 127 ? 127 : hs);
        int pc = ps < 0 ? 0 : (ps > 127 ? 127 : ps);
        const ushort* sb = src ? inter_clh : x_clh;
        short8 v = *(const short8*)(sb + ((size_t)(bbase + (hc << 7) + pc)) * 64 + ch);
        short8 z = {0, 0, 0, 0, 0, 0, 0, 0};
        if (!ok) v = z;
        *(short8*)(&BIGB[e * CPITCH + ch]) = v;
      }
    }
  }
  LGKM_BAR();   // B0: halo visible (ds_writes drained; no vmcnt drain)

  // ---- phase 2: conv MFMAs -> registers (oml store deferred past barrier) ----
  f32x4 accx = {0.f, 0.f, 0.f, 0.f}, acci = {0.f, 0.f, 0.f, 0.f};
  {
    const ushort* wb0 = wfb + (size_t)(mt * 16 + col) * 128 + quad * 8;
    int pxb = pt * 16 + col;
#pragma unroll
    for (int ky = 0; ky < 3; ++ky) {
#pragma unroll
      for (int kx = 0; kx < 3; ++kx) {
        int tap = ky * 3 + kx;
        const ushort* wt = wb0 + (size_t)tap * 4096;
#pragma unroll
        for (int ks = 0; ks < 2; ++ks) {
          short8 a0 = *(const short8*)(wt + ks * 32);
          short8 b0 = *(const short8*)(&BIGB[(ky * 34 + pxb + kx) * CPITCH + ks * 32 + quad * 8]);
          accx = __builtin_amdgcn_mfma_f32_16x16x32_bf16(a0, b0, accx, 0, 0, 0);
          short8 a1 = *(const short8*)(wt + 64 + ks * 32);
          short8 b1 = *(const short8*)(&BIGB[((3 + ky) * 34 + pxb + kx) * CPITCH + ks * 32 + quad * 8]);
          acci = __builtin_amdgcn_mfma_f32_16x16x32_bf16(a1, b1, acci, 0, 0, 0);
        }
      }
    }
  }
  LGKM_BAR();   // B1: halo reads done; BIGB free for aliases

  // oml store into BIGB tail (disjoint from Sg/Sb written in phase 3).
#pragma unroll
  for (int r = 0; r < 4; ++r) {
    int o = mt * 16 + quad * 4 + r;
    if (o < 27) oml[o * 33 + pt * 16 + col] = accx[r] + acci[r];
  }

  // ---- phase 3: SFT stage A -> Sg/Sb ----
  f32x4 ag[2], ab[2];
#pragma unroll
  for (int nt = 0; nt < 2; ++nt) {
    ag[nt] = (f32x4){0.f, 0.f, 0.f, 0.f};
    ab[nt] = (f32x4){0.f, 0.f, 0.f, 0.f};
  }
#pragma unroll
  for (int ks = 0; ks < 2; ++ks) {
    short8 a_g = *(const short8*)(w1gb + (size_t)(o_base + col) * 64 + ks * 32 + quad * 8);
    short8 a_b = *(const short8*)(w1bb + (size_t)(o_base + col) * 64 + ks * 32 + quad * 8);
#pragma unroll
    for (int nt = 0; nt < 2; ++nt) {
      short8 bf = *(const short8*)(inter_clh + (size_t)(pg0 + nt * 16 + col) * 64 + ks * 32 + quad * 8);
      ag[nt] = __builtin_amdgcn_mfma_f32_16x16x32_bf16(a_g, bf, ag[nt], 0, 0, 0);
      ab[nt] = __builtin_amdgcn_mfma_f32_16x16x32_bf16(a_b, bf, ab[nt], 0, 0, 0);
    }
  }
#pragma unroll
  for (int nt = 0; nt < 2; ++nt) {
    int px = nt * 16 + col;
    ushort pkg[4], pkb[4];
#pragma unroll
    for (int r = 0; r < 4; ++r) {
      float vg = ag[nt][r]; vg = vg >= 0.f ? vg : 0.1f * vg;
      float vb = ab[nt][r]; vb = vb >= 0.f ? vb : 0.1f * vb;
      pkg[r] = f2bf(vg); pkb[r] = f2bf(vb);
    }
    *(uint2*)(&Sg[px * FPX + o_base + quad * 4]) = *(uint2*)pkg;
    *(uint2*)(&Sb[px * FPX + o_base + quad * 4]) = *(uint2*)pkb;
  }
  LGKM_BAR();   // B2: oml + Sg/Sb visible

  // ---- phase 4: SFT stage B -> gamma/beta in registers ----
  f32x4 gg[2], gb[2];
#pragma unroll
  for (int nt = 0; nt < 2; ++nt) {
    gg[nt] = (f32x4){0.f, 0.f, 0.f, 0.f};
    gb[nt] = (f32x4){0.f, 0.f, 0.f, 0.f};
  }
#pragma unroll
  for (int ks = 0; ks < 2; ++ks) {
    short8 a_g = *(const short8*)(w2gb + (size_t)(o_base + col) * 64 + ks * 32 + quad * 8);
    short8 a_b = *(const short8*)(w2bb + (size_t)(o_base + col) * 64 + ks * 32 + quad * 8);
#pragma unroll
    for (int nt = 0; nt < 2; ++nt) {
      short8 bgf = *(const short8*)(Sg + (nt * 16 + col) * FPX + ks * 32 + quad * 8);
      short8 bbf = *(const short8*)(Sb + (nt * 16 + col) * FPX + ks * 32 + quad * 8);
      gg[nt] = __builtin_amdgcn_mfma_f32_16x16x32_bf16(a_g, bgf, gg[nt], 0, 0, 0);
      gb[nt] = __builtin_amdgcn_mfma_f32_16x16x32_bf16(a_b, bbf, gb[nt], 0, 0, 0);
    }
  }
  // Prefetch epilogue x values — with lgkm-only barriers these loads stay
  // in flight until the epilogue (no drain at any barrier below).
  float xv[2][4];
#pragma unroll
  for (int nt = 0; nt < 2; ++nt)
#pragma unroll
    for (int r = 0; r < 4; ++r) {
      int o = o_base + quad * 4 + r;
      xv[nt][r] = x[(size_t)(b * 64 + o) * HW + hw0 + nt * 16 + col];
    }
  LGKM_BAR();   // B3: Sg/Sb reads done; region becomes coords

  // ---- phase 5: coords once per (pixel, tap) from om_local ----
  for (int i = tid; i < 9 * NPX; i += 256) {
    int k = i >> 5, p = i & 31;
    float dy = oml[k * 33 + p] + b_off[k];
    float dx = oml[(9 + k) * 33 + p] + b_off[9 + k];
    float mz = oml[(18 + k) * 33 + p] + b_off[18 + k];
    float py = (float)(h + (k / 3) - 1) + dy;
    float px = (float)(w0 + p + (k % 3) - 1) + dx;
    float y0f = floorf(py), x0f = floorf(px);
    cy[i] = (int)y0f;
    cx[i] = (int)x0f;
    cwy[i] = py - y0f;
    cwx[i] = px - x0f;
    cm[i] = 1.f / (1.f + __expf(-mz));
  }

  f32x4 acc[2];
  acc[0] = (f32x4){0.f, 0.f, 0.f, 0.f};
  acc[1] = (f32x4){0.f, 0.f, 0.f, 0.f};

  const ushort* bp = x_clh + (size_t)b * HW * 64;
  int p = wave * 8 + rr;

  // ---- phase 6: gather + MFMA, cross-barrier pipelined corner bank ----
  short8 k00[3], k01[3], k10[3], k11[3];
  float kwy[3], kwx[3], km[3];

  LGKM_BAR();   // B4: coords ready

  // prologue: chunk 0 corners (only exposed gather latency in the loop)
#pragma unroll
  for (int it = 0; it < 3; ++it) {
    int idx = it * NPX + p;
    int y0 = cy[idx], x0 = cx[idx];
    kwy[it] = cwy[idx]; kwx[it] = cwx[idx]; km[it] = cm[idx];
    bool yok0 = (unsigned)y0 < 128u, yok1 = (unsigned)(y0 + 1) < 128u;
    bool xok0 = (unsigned)x0 < 128u, xok1 = (unsigned)(x0 + 1) < 128u;
    const ushort* r0 = bp + ((size_t)(int)((y0 << 7) + x0)) * 64 + g * 8;
    const ushort* r1 = r0 + (size_t)WW * 64;
    k00[it] = *(const short8*)((yok0 && xok0) ? r0 : zp16);
    k01[it] = *(const short8*)((yok0 && xok1) ? (r0 + 64) : zp16);
    k10[it] = *(const short8*)((yok1 && xok0) ? r1 : zp16);
    k11[it] = *(const short8*)((yok1 && xok1) ? (r1 + 64) : zp16);
  }

#pragma unroll 1
  for (int chunk = 0; chunk < 3; ++chunk) {
    if (chunk) LGKM_BAR();           // S free (prev MFMA ds_reads done)
    // bilerp current bank -> S
#pragma unroll
    for (int it = 0; it < 3; ++it) {
      float wy = kwy[it], wx = kwx[it], m = km[it];
      short8 outv;
#pragma unroll
      for (int j = 0; j < 8; ++j) {
        float v00 = bf2f((ushort)k00[it][j]), v01 = bf2f((ushort)k01[it][j]);
        float v10 = bf2f((ushort)k10[it][j]), v11 = bf2f((ushort)k11[it][j]);
        float top = v00 + (v01 - v00) * wx;
        float bot = v10 + (v11 - v10) * wx;
        float val = top + (bot - top) * wy;
        outv[j] = (short)f2bf(val * m);
      }
      *(short8*)(&S[p * SPITCH + it * 64 + g * 8]) = outv;
    }
    // issue NEXT chunk's loads; with lgkm-only barriers they remain in
    // flight across S-ready + MFMA + S-free and complete under them.
    if (chunk < 2) {
#pragma unroll
      for (int it = 0; it < 3; ++it) {
        int idx = ((chunk + 1) * 3 + it) * NPX + p;
        int y0 = cy[idx], x0 = cx[idx];
        kwy[it] = cwy[idx]; kwx[it] = cwx[idx]; km[it] = cm[idx];
        bool yok0 = (unsigned)y0 < 128u, yok1 = (unsigned)(y0 + 1) < 128u;
        bool xok0 = (unsigned)x0 < 128u, xok1 = (unsigned)(x0 + 1) < 128u;
        const ushort* r0 = bp + ((size_t)(int)((y0 << 7) + x0)) * 64 + g * 8;
        const ushort* r1 = r0 + (size_t)WW * 64;
        k00[it] = *(const short8*)((yok0 && xok0) ? r0 : zp16);
        k01[it] = *(const short8*)((yok0 && xok1) ? (r0 + 64) : zp16);
        k10[it] = *(const short8*)((yok1 && xok0) ? r1 : zp16);
        k11[it] = *(const short8*)((yok1 && xok1) ? (r1 + 64) : zp16);
      }
    }
    LGKM_BAR();                      // S ready (ds_writes drained only)
    const ushort* wrow = wdT + (size_t)(o_base + col) * 576 + chunk * 192 + quad * 8;
    const ushort* srow = S + quad * 8;
#pragma unroll
    for (int ks = 0; ks < 6; ++ks) {
      short8 a = *(const short8*)(wrow + ks * 32);
#pragma unroll
      for (int nt = 0; nt < 2; ++nt) {
        short8 bf = *(const short8*)(srow + (nt * 16 + col) * SPITCH + ks * 32);
        acc[nt] = __builtin_amdgcn_mfma_f32_16x16x32_bf16(a, bf, acc[nt], 0, 0, 0);
      }
    }
  }

  // ---- phase 7: epilogue: out = x + x*gamma + beta + dcn (single write) ----
#pragma unroll
  for (int nt = 0; nt < 2; ++nt) {
#pragma unroll
    for (int r = 0; r < 4; ++r) {
      int o = o_base + quad * 4 + r;
      size_t idx = (size_t)(b * 64 + o) * HW + hw0 + nt * 16 + col;
      out[idx] = xv[nt][r] + xv[nt][r] * gg[nt][r] + gb[nt][r] + acc[nt][r];
    }
  }
}

// ---------------------------------------------------------------------------
// Workspace plan (float slots), compacted ~17 MB (r4-verified):
//   x_clh     ushort [0        .. 2097152)
//   inter_clh ushort [2097152  .. 4194304)
//   wfb       ushort [4194304  .. 4212736)
//   wdT       ushort [4212736  .. 4231168)
//   w1gb/w1bb/w2gb/w2bb ushort 4 x 2048 float slots [4231168 .. 4239360)
//   zp        fp32   [4239360  .. 4239424)
// ---------------------------------------------------------------------------
extern "C" void kernel_launch(void* const* d_in, const int* in_sizes, int n_in,
                              void* d_out, int out_size, void* d_ws, size_t ws_size,
                              hipStream_t stream) {
  const float* x     = (const float*)d_in[0];
  const float* inter = (const float*)d_in[1];
  const float* w_off = (const float*)d_in[2];
  const float* b_off = (const float*)d_in[3];
  const float* w_dcn = (const float*)d_in[4];
  const float* wg1   = (const float*)d_in[5];
  const float* wg2   = (const float*)d_in[6];
  const float* wb1   = (const float*)d_in[7];
  const float* wb2   = (const float*)d_in[8];
  float* out = (float*)d_out;

  float* ws        = (float*)d_ws;
  ushort* x_clh    = (ushort*)ws;
  ushort* inter_clh= (ushort*)(ws + 2097152);
  ushort* wfb      = (ushort*)(ws + 4194304);
  ushort* wdT      = (ushort*)(ws + 4212736);
  ushort* w1gb     = (ushort*)(ws + 4231168);
  ushort* w1bb     = (ushort*)(ws + 4233216);
  ushort* w2gb     = (ushort*)(ws + 4235264);
  ushort* w2bb     = (ushort*)(ws + 4237312);
  float* zp        = ws + 4239360;

  // Prep: channels-last bf16 inputs + all packed weights + zero page.
  k_prep<<<1376, 256, 0, stream>>>(x, inter, w_off, w_dcn, wg1, wb1, wg2, wb2,
                                   x_clh, inter_clh, wfb, wdT,
                                   w1gb, w1bb, w2gb, w2bb, zp);

  // Fully fused conv + SFT + DCN (r7 structure + lgkm-only barriers +
  // cross-barrier gather pipeline).
  k_omega<<<2048, 256, 0, stream>>>(x, x_clh, inter_clh, b_off, wfb, wdT,
                                    w1gb, w1bb, w2gb, w2bb,
                                    (const ushort*)zp, out);
}

// Round 10
// 172.252 us; speedup vs baseline: 1.3949x; 1.0015x over previous
//
#include <hip/hip_runtime.h>
#include <hip/hip_bf16.h>
#include <math.h>

#define BB 4
#define CC 64
#define HH 128
#define WW 128
#define HW (HH*WW)          // 16384
#define NPIX (BB*HW)        // 65536

typedef __attribute__((ext_vector_type(8))) short short8;   // 8 bf16
typedef __attribute__((ext_vector_type(4))) float f32x4;

__device__ __forceinline__ float bf2f(ushort u) {
  union { unsigned u; float f; } v; v.u = ((unsigned)u) << 16; return v.f;
}
__device__ __forceinline__ ushort f2bf(float f) {
  __hip_bfloat16 h = __float2bfloat16(f); return *(ushort*)&h;
}

// ---------------------------------------------------------------------------
// Prep (verified, unchanged): NCHW fp32 -> channels-last bf16 + weights.
// ---------------------------------------------------------------------------
__global__ __launch_bounds__(256) void k_prep(
    const float* __restrict__ x, const float* __restrict__ inter,
    const float* __restrict__ w_off, const float* __restrict__ w_dcn,
    const float* __restrict__ wg1, const float* __restrict__ wb1,
    const float* __restrict__ wg2, const float* __restrict__ wb2,
    ushort* __restrict__ x_clh, ushort* __restrict__ inter_clh,
    ushort* __restrict__ wfb, ushort* __restrict__ wdT,
    ushort* __restrict__ w1gb, ushort* __restrict__ w1bb,
    ushort* __restrict__ w2gb, ushort* __restrict__ w2bb,
    float* __restrict__ zp) {
  __shared__ __align__(16) float tile[64 * 128];   // 32 KiB, xor-swizzled
  int blk = blockIdx.x;
  int tid = threadIdx.x;
  if (blk < 1024) {
    int sel = blk >> 9;
    int bh = blk & 511;
    int b = bh >> 7, h = bh & 127;
    const float* src = sel ? inter : x;
    ushort* dst = sel ? inter_clh : x_clh;
    const float* sp = src + (size_t)(b * 64) * HW + h * WW;
#pragma unroll
    for (int it = 0; it < 8; ++it) {
      int idx = it * 256 + tid;
      int c = idx >> 5, wq = idx & 31;
      float4 v = *(const float4*)(sp + (size_t)c * HW + wq * 4);
      int s = (c >> 3) & 7;
      *(float4*)(&tile[c * 128 + ((wq ^ s) << 2)]) = v;
    }
    __syncthreads();
    ushort* dp = dst + ((size_t)b * HW + h * WW) * 64;
#pragma unroll
    for (int it = 0; it < 4; ++it) {
      int idx = it * 256 + tid;
      int w = idx >> 3, c8 = idx & 7;
      short8 outv;
#pragma unroll
      for (int j = 0; j < 8; ++j) {
        int c = c8 * 8 + j;
        int sl = (w >> 2) ^ c8;
        float f = tile[c * 128 + (sl << 2) + (w & 3)];
        outv[j] = (short)f2bf(f);
      }
      *(short8*)(dp + (size_t)w * 64 + c8 * 8) = outv;
    }
  } else if (blk < 1168) {
    int i = (blk - 1024) * 256 + tid;
    if (i < 64) zp[i] = 0.f;
    if (i < 9 * 32 * 128) {
      int tap = i >> 12, rem = i & 4095, m = rem >> 7, c = rem & 127;
      float v = (m < 27) ? w_off[(size_t)(m * 128 + c) * 9 + tap] : 0.f;
      wfb[i] = f2bf(v);
    }
  } else if (blk < 1312) {
    int i = (blk - 1168) * 256 + tid;
    if (i < 64 * 64 * 9) {
      int o = i / 576, rem = i % 576, k = rem >> 6, c = rem & 63;
      wdT[i] = f2bf(w_dcn[(o * 64 + c) * 9 + k]);
    }
  } else {
    int i = (blk - 1312) * 256 + tid;   // 0..16383
    int m = i >> 12, j = i & 4095;
    const float* src = (m == 0) ? wg1 : (m == 1) ? wb1 : (m == 2) ? wg2 : wb2;
    ushort* dst = (m == 0) ? w1gb : (m == 1) ? w1bb : (m == 2) ? w2gb : w2bb;
    dst[j] = f2bf(src[j]);
  }
}

// ---------------------------------------------------------------------------
// OMEGA v10 = round-7 kernel (best, 84 us) + split-halo LDS diet -> 8 blk/CU.
//  The ONLY surviving theory after 9 rounds: residency rounds. LDS 29696 ->
//  5 blocks/CU resident vs 8 blocks/CU of work = 2 serial generations;
//  duration ~= 2x per-block critical path. This version stages the conv halo
//  in TWO passes (x-halo -> conv-x MFMAs -> restage inter-halo -> conv-inter
//  MFMAs) in a 14688 B buffer: same loads, same MFMAs, +2 barriers.
//  Total LDS 18560 B -> 8 blocks/CU (163840/18560 = 8.8). VGPR natural
//  (~52-60, NO clamp -> no spills; both spill disasters came from clamps).
//  Everything else byte-identical to r7 (XCD swizzle kept, plain barriers
//  kept per r9's null lgkm result).
// LDS alias map (18560 B total; all serial reuse, barrier-separated):
//   [0,14688)      conv passes: halo 102 rows x 72 shorts (x, then inter)
//   [0,9216)       ph3-4: Sg [0,4608) + Sb [4608,9216)
//   [9216,12780)   ph3-5: oml 27 x 33 f32 (written after conv-i barrier)
//   [0,5760)       ph5-6: coords cy/cx/cwy/cwx/cm (5 x 288 x 4 B)
//   [5760,18560)   ph6:   S gather buffer 32 px x 200 shorts (oml dead)
// ---------------------------------------------------------------------------
#define CPITCH 72    // shorts per (row, px) channel row in conv halo
#define SPITCH 200   // shorts per pixel row in gather buffer S
#define NPX 32       // pixels per block
#define FPX 72       // shorts per px row in Sg/Sb

__global__ __launch_bounds__(256) void k_omega(
    const float* __restrict__ x, const ushort* __restrict__ x_clh,
    const ushort* __restrict__ inter_clh,
    const float* __restrict__ b_off, const ushort* __restrict__ wfb,
    const ushort* __restrict__ wdT,
    const ushort* __restrict__ w1gb, const ushort* __restrict__ w1bb,
    const ushort* __restrict__ w2gb, const ushort* __restrict__ w2bb,
    const ushort* __restrict__ zp16, float* __restrict__ out) {
  __shared__ __align__(16) ushort LDSB[9280];            // 18560 B total
  ushort* halo = LDSB;                    // 102 x 72 shorts (both conv passes)
  ushort* Sg = LDSB;                      // 2304 shorts  (ph3-4)
  ushort* Sb = LDSB + 2304;               // 2304 shorts
  float* oml = (float*)(LDSB + 4608);     // byte 9216: 27x33 f32 (ph3-5)
  int*   cy  = (int*)LDSB;                // ph5-6 coords: 288 each
  int*   cx  = cy + 288;
  float* cwy = (float*)(cx + 288);
  float* cwx = cwy + 288;
  float* cm  = cwx + 288;                 // ends byte 5760
  ushort* S  = LDSB + 2880;               // byte 5760: 32 x 200 shorts (ph6)

  int tid = threadIdx.x;
  int wave = tid >> 6, lane = tid & 63;
  int quad = lane >> 4, col = lane & 15;
  int rr = lane >> 3, g = lane & 7;
  // XCD-chunked swizzle (r7: FETCH -36%, kept).
  int bid = blockIdx.x;
  int wid = (bid & 7) * 256 + (bid >> 3);
  int pg0 = wid * NPX;
  int b = pg0 >> 14, hw0 = pg0 & 16383;
  int h = hw0 >> 7, w0 = hw0 & 127;
  int pt = wave >> 1, mt = wave & 1;
  int o_base = __builtin_amdgcn_readfirstlane(wave * 16);

  // ---- conv: two staged passes (x then inter) through the 102-row halo ----
  f32x4 accx = {0.f, 0.f, 0.f, 0.f}, acci = {0.f, 0.f, 0.f, 0.f};
  {
    int ch = (tid & 7) * 8;
    unsigned bbase = (unsigned)b * HW;
    const ushort* wb0 = wfb + (size_t)(mt * 16 + col) * 128 + quad * 8;
    int pxb = pt * 16 + col;
#pragma unroll 1
    for (int pass = 0; pass < 2; ++pass) {
      const ushort* sb = pass ? inter_clh : x_clh;
      // stage 3 rows x 34 px of this source
#pragma unroll
      for (int it = 0; it < 4; ++it) {
        int e = it * 32 + (tid >> 3);
        if (e < 102) {
          int row = e / 34, pxl = e % 34;
          int hs = h + row - 1;
          int ps = w0 + pxl - 1;
          bool ok = ((unsigned)hs < 128u) && ((unsigned)ps < 128u);
          int hc = hs < 0 ? 0 : (hs > 127 ? 127 : hs);
          int pc = ps < 0 ? 0 : (ps > 127 ? 127 : ps);
          short8 v = *(const short8*)(sb + ((size_t)(bbase + (hc << 7) + pc)) * 64 + ch);
          short8 z = {0, 0, 0, 0, 0, 0, 0, 0};
          if (!ok) v = z;
          *(short8*)(&halo[e * CPITCH + ch]) = v;
        }
      }
      __syncthreads();   // halo(pass) visible
      int aoff = pass ? 64 : 0;   // wfb c-slice: x = [0,64), inter = [64,128)
      f32x4 accp = {0.f, 0.f, 0.f, 0.f};
#pragma unroll
      for (int ky = 0; ky < 3; ++ky) {
#pragma unroll
        for (int kx = 0; kx < 3; ++kx) {
          int tap = ky * 3 + kx;
          const ushort* wt = wb0 + (size_t)tap * 4096 + aoff;
#pragma unroll
          for (int ks = 0; ks < 2; ++ks) {
            short8 a0 = *(const short8*)(wt + ks * 32);
            short8 b0 = *(const short8*)(&halo[(ky * 34 + pxb + kx) * CPITCH + ks * 32 + quad * 8]);
            accp = __builtin_amdgcn_mfma_f32_16x16x32_bf16(a0, b0, accp, 0, 0, 0);
          }
        }
      }
      if (pass) acci = accp; else accx = accp;
      __syncthreads();   // halo reads done; buffer free (restage or aliases)
    }
  }

  // oml store (halo dead; oml region [9216,12780) now safe).
#pragma unroll
  for (int r = 0; r < 4; ++r) {
    int o = mt * 16 + quad * 4 + r;
    if (o < 27) oml[o * 33 + pt * 16 + col] = accx[r] + acci[r];
  }

  // ---- phase 3: SFT stage A -> Sg/Sb ----
  f32x4 ag[2], ab[2];
#pragma unroll
  for (int nt = 0; nt < 2; ++nt) {
    ag[nt] = (f32x4){0.f, 0.f, 0.f, 0.f};
    ab[nt] = (f32x4){0.f, 0.f, 0.f, 0.f};
  }
#pragma unroll
  for (int ks = 0; ks < 2; ++ks) {
    short8 a_g = *(const short8*)(w1gb + (size_t)(o_base + col) * 64 + ks * 32 + quad * 8);
    short8 a_b = *(const short8*)(w1bb + (size_t)(o_base + col) * 64 + ks * 32 + quad * 8);
#pragma unroll
    for (int nt = 0; nt < 2; ++nt) {
      short8 bf = *(const short8*)(inter_clh + (size_t)(pg0 + nt * 16 + col) * 64 + ks * 32 + quad * 8);
      ag[nt] = __builtin_amdgcn_mfma_f32_16x16x32_bf16(a_g, bf, ag[nt], 0, 0, 0);
      ab[nt] = __builtin_amdgcn_mfma_f32_16x16x32_bf16(a_b, bf, ab[nt], 0, 0, 0);
    }
  }
#pragma unroll
  for (int nt = 0; nt < 2; ++nt) {
    int px = nt * 16 + col;
    ushort pkg[4], pkb[4];
#pragma unroll
    for (int r = 0; r < 4; ++r) {
      float vg = ag[nt][r]; vg = vg >= 0.f ? vg : 0.1f * vg;
      float vb = ab[nt][r]; vb = vb >= 0.f ? vb : 0.1f * vb;
      pkg[r] = f2bf(vg); pkb[r] = f2bf(vb);
    }
    *(uint2*)(&Sg[px * FPX + o_base + quad * 4]) = *(uint2*)pkg;
    *(uint2*)(&Sb[px * FPX + o_base + quad * 4]) = *(uint2*)pkb;
  }
  __syncthreads();   // B: oml + Sg/Sb visible

  // ---- phase 4: SFT stage B -> gamma/beta in registers ----
  f32x4 gg[2], gb[2];
#pragma unroll
  for (int nt = 0; nt < 2; ++nt) {
    gg[nt] = (f32x4){0.f, 0.f, 0.f, 0.f};
    gb[nt] = (f32x4){0.f, 0.f, 0.f, 0.f};
  }
#pragma unroll
  for (int ks = 0; ks < 2; ++ks) {
    short8 a_g = *(const short8*)(w2gb + (size_t)(o_base + col) * 64 + ks * 32 + quad * 8);
    short8 a_b = *(const short8*)(w2bb + (size_t)(o_base + col) * 64 + ks * 32 + quad * 8);
#pragma unroll
    for (int nt = 0; nt < 2; ++nt) {
      short8 bgf = *(const short8*)(Sg + (nt * 16 + col) * FPX + ks * 32 + quad * 8);
      short8 bbf = *(const short8*)(Sb + (nt * 16 + col) * FPX + ks * 32 + quad * 8);
      gg[nt] = __builtin_amdgcn_mfma_f32_16x16x32_bf16(a_g, bgf, gg[nt], 0, 0, 0);
      gb[nt] = __builtin_amdgcn_mfma_f32_16x16x32_bf16(a_b, bbf, gb[nt], 0, 0, 0);
    }
  }
  // Prefetch epilogue x values (independent of everything below).
  float xv[2][4];
#pragma unroll
  for (int nt = 0; nt < 2; ++nt)
#pragma unroll
    for (int r = 0; r < 4; ++r) {
      int o = o_base + quad * 4 + r;
      xv[nt][r] = x[(size_t)(b * 64 + o) * HW + hw0 + nt * 16 + col];
    }
  __syncthreads();   // B: Sg/Sb dead; region becomes coords

  // ---- phase 5: coords once per (pixel, tap) from om_local ----
  for (int i = tid; i < 9 * NPX; i += 256) {
    int k = i >> 5, p = i & 31;
    float dy = oml[k * 33 + p] + b_off[k];
    float dx = oml[(9 + k) * 33 + p] + b_off[9 + k];
    float mz = oml[(18 + k) * 33 + p] + b_off[18 + k];
    float py = (float)(h + (k / 3) - 1) + dy;
    float px = (float)(w0 + p + (k % 3) - 1) + dx;
    float y0f = floorf(py), x0f = floorf(px);
    cy[i] = (int)y0f;
    cx[i] = (int)x0f;
    cwy[i] = py - y0f;
    cwx[i] = px - x0f;
    cm[i] = 1.f / (1.f + __expf(-mz));
  }

  f32x4 acc[2];
  acc[0] = (f32x4){0.f, 0.f, 0.f, 0.f};
  acc[1] = (f32x4){0.f, 0.f, 0.f, 0.f};

  const ushort* bp = x_clh + (size_t)b * HW * 64;

  // ---- phase 6: gather + MFMA chunks (S overlays dead oml) ----
  for (int chunk = 0; chunk < 3; ++chunk) {
    __syncthreads();   // chunk 0: coords ready (oml dead); later: S free
#pragma unroll
    for (int it = 0; it < 3; ++it) {
      int p = wave * 8 + rr;
      int idx = (chunk * 3 + it) * NPX + p;
      int y0 = cy[idx], x0 = cx[idx];
      float wy = cwy[idx], wx = cwx[idx], m = cm[idx];
      bool yok0 = (unsigned)y0 < 128u, yok1 = (unsigned)(y0 + 1) < 128u;
      bool xok0 = (unsigned)x0 < 128u, xok1 = (unsigned)(x0 + 1) < 128u;
      const ushort* r0 = bp + ((size_t)(int)((y0 << 7) + x0)) * 64 + g * 8;
      const ushort* r1 = r0 + (size_t)WW * 64;
      short8 s00 = *(const short8*)((yok0 && xok0) ? r0 : zp16);
      short8 s01 = *(const short8*)((yok0 && xok1) ? (r0 + 64) : zp16);
      short8 s10 = *(const short8*)((yok1 && xok0) ? r1 : zp16);
      short8 s11 = *(const short8*)((yok1 && xok1) ? (r1 + 64) : zp16);
      short8 outv;
#pragma unroll
      for (int j = 0; j < 8; ++j) {
        float v00 = bf2f((ushort)s00[j]), v01 = bf2f((ushort)s01[j]);
        float v10 = bf2f((ushort)s10[j]), v11 = bf2f((ushort)s11[j]);
        float top = v00 + (v01 - v00) * wx;
        float bot = v10 + (v11 - v10) * wx;
        float val = top + (bot - top) * wy;
        outv[j] = (short)f2bf(val * m);
      }
      *(short8*)(&S[p * SPITCH + it * 64 + g * 8]) = outv;
    }
    __syncthreads();
    const ushort* wrow = wdT + (size_t)(o_base + col) * 576 + chunk * 192 + quad * 8;
    const ushort* srow = S + quad * 8;
#pragma unroll
    for (int ks = 0; ks < 6; ++ks) {
      short8 a = *(const short8*)(wrow + ks * 32);
#pragma unroll
      for (int nt = 0; nt < 2; ++nt) {
        short8 bf = *(const short8*)(srow + (nt * 16 + col) * SPITCH + ks * 32);
        acc[nt] = __builtin_amdgcn_mfma_f32_16x16x32_bf16(a, bf, acc[nt], 0, 0, 0);
      }
    }
  }

  // ---- phase 7: epilogue: out = x + x*gamma + beta + dcn (single write) ----
#pragma unroll
  for (int nt = 0; nt < 2; ++nt) {
#pragma unroll
    for (int r = 0; r < 4; ++r) {
      int o = o_base + quad * 4 + r;
      size_t idx = (size_t)(b * 64 + o) * HW + hw0 + nt * 16 + col;
      out[idx] = xv[nt][r] + xv[nt][r] * gg[nt][r] + gb[nt][r] + acc[nt][r];
    }
  }
}

// ---------------------------------------------------------------------------
// Workspace plan (float slots), compacted ~17 MB (r4-verified):
//   x_clh     ushort [0        .. 2097152)
//   inter_clh ushort [2097152  .. 4194304)
//   wfb       ushort [4194304  .. 4212736)
//   wdT       ushort [4212736  .. 4231168)
//   w1gb/w1bb/w2gb/w2bb ushort 4 x 2048 float slots [4231168 .. 4239360)
//   zp        fp32   [4239360  .. 4239424)
// ---------------------------------------------------------------------------
extern "C" void kernel_launch(void* const* d_in, const int* in_sizes, int n_in,
                              void* d_out, int out_size, void* d_ws, size_t ws_size,
                              hipStream_t stream) {
  const float* x     = (const float*)d_in[0];
  const float* inter = (const float*)d_in[1];
  const float* w_off = (const float*)d_in[2];
  const float* b_off = (const float*)d_in[3];
  const float* w_dcn = (const float*)d_in[4];
  const float* wg1   = (const float*)d_in[5];
  const float* wg2   = (const float*)d_in[6];
  const float* wb1   = (const float*)d_in[7];
  const float* wb2   = (const float*)d_in[8];
  float* out = (float*)d_out;

  float* ws        = (float*)d_ws;
  ushort* x_clh    = (ushort*)ws;
  ushort* inter_clh= (ushort*)(ws + 2097152);
  ushort* wfb      = (ushort*)(ws + 4194304);
  ushort* wdT      = (ushort*)(ws + 4212736);
  ushort* w1gb     = (ushort*)(ws + 4231168);
  ushort* w1bb     = (ushort*)(ws + 4233216);
  ushort* w2gb     = (ushort*)(ws + 4235264);
  ushort* w2bb     = (ushort*)(ws + 4237312);
  float* zp        = ws + 4239360;

  // Prep: channels-last bf16 inputs + all packed weights + zero page.
  k_prep<<<1376, 256, 0, stream>>>(x, inter, w_off, w_dcn, wg1, wb1, wg2, wb2,
                                   x_clh, inter_clh, wfb, wdT,
                                   w1gb, w1bb, w2gb, w2bb, zp);

  // Fully fused conv + SFT + DCN (v10: split-halo, 18560 B LDS, 8 blk/CU).
  k_omega<<<2048, 256, 0, stream>>>(x, x_clh, inter_clh, b_off, wfb, wdT,
                                    w1gb, w1bb, w2gb, w2bb,
                                    (const ushort*)zp, out);
}

// Round 11
// 171.376 us; speedup vs baseline: 1.4020x; 1.0051x over previous
//
#include <hip/hip_runtime.h>
#include <hip/hip_bf16.h>
#include <math.h>

#define BB 4
#define CC 64
#define HH 128
#define WW 128
#define HW (HH*WW)          // 16384
#define NPIX (BB*HW)        // 65536

typedef __attribute__((ext_vector_type(8))) short short8;   // 8 bf16
typedef __attribute__((ext_vector_type(4))) float f32x4;

__device__ __forceinline__ float bf2f(ushort u) {
  union { unsigned u; float f; } v; v.u = ((unsigned)u) << 16; return v.f;
}
__device__ __forceinline__ ushort f2bf(float f) {
  __hip_bfloat16 h = __float2bfloat16(f); return *(ushort*)&h;
}

// ---------------------------------------------------------------------------
// Prep (round-1 verified): NCHW fp32 -> channels-last bf16 + weights.
// ---------------------------------------------------------------------------
__global__ __launch_bounds__(256) void k_prep(
    const float* __restrict__ x, const float* __restrict__ inter,
    const float* __restrict__ w_off, const float* __restrict__ w_dcn,
    const float* __restrict__ wg1, const float* __restrict__ wb1,
    const float* __restrict__ wg2, const float* __restrict__ wb2,
    ushort* __restrict__ x_clh, ushort* __restrict__ inter_clh,
    ushort* __restrict__ wfb, ushort* __restrict__ wdT,
    ushort* __restrict__ w1gb, ushort* __restrict__ w1bb,
    ushort* __restrict__ w2gb, ushort* __restrict__ w2bb,
    float* __restrict__ zp) {
  __shared__ __align__(16) float tile[64 * 128];   // 32 KiB, xor-swizzled
  int blk = blockIdx.x;
  int tid = threadIdx.x;
  if (blk < 1024) {
    int sel = blk >> 9;
    int bh = blk & 511;
    int b = bh >> 7, h = bh & 127;
    const float* src = sel ? inter : x;
    ushort* dst = sel ? inter_clh : x_clh;
    const float* sp = src + (size_t)(b * 64) * HW + h * WW;
#pragma unroll
    for (int it = 0; it < 8; ++it) {
      int idx = it * 256 + tid;
      int c = idx >> 5, wq = idx & 31;
      float4 v = *(const float4*)(sp + (size_t)c * HW + wq * 4);
      int s = (c >> 3) & 7;
      *(float4*)(&tile[c * 128 + ((wq ^ s) << 2)]) = v;
    }
    __syncthreads();
    ushort* dp = dst + ((size_t)b * HW + h * WW) * 64;
#pragma unroll
    for (int it = 0; it < 4; ++it) {
      int idx = it * 256 + tid;
      int w = idx >> 3, c8 = idx & 7;
      short8 outv;
#pragma unroll
      for (int j = 0; j < 8; ++j) {
        int c = c8 * 8 + j;
        int sl = (w >> 2) ^ c8;
        float f = tile[c * 128 + (sl << 2) + (w & 3)];
        outv[j] = (short)f2bf(f);
      }
      *(short8*)(dp + (size_t)w * 64 + c8 * 8) = outv;
    }
  } else if (blk < 1168) {
    int i = (blk - 1024) * 256 + tid;
    if (i < 64) zp[i] = 0.f;
    if (i < 9 * 32 * 128) {
      int tap = i >> 12, rem = i & 4095, m = rem >> 7, c = rem & 127;
      float v = (m < 27) ? w_off[(size_t)(m * 128 + c) * 9 + tap] : 0.f;
      wfb[i] = f2bf(v);
    }
  } else if (blk < 1312) {
    int i = (blk - 1168) * 256 + tid;
    if (i < 64 * 64 * 9) {
      int o = i / 576, rem = i % 576, k = rem >> 6, c = rem & 63;
      wdT[i] = f2bf(w_dcn[(o * 64 + c) * 9 + k]);
    }
  } else {
    int i = (blk - 1312) * 256 + tid;   // 0..16383
    int m = i >> 12, j = i & 4095;
    const float* src = (m == 0) ? wg1 : (m == 1) ? wb1 : (m == 2) ? wg2 : wb2;
    ushort* dst = (m == 0) ? w1gb : (m == 1) ? w1bb : (m == 2) ? w2gb : w2bb;
    dst[j] = f2bf(src[j]);
  }
}

// ---------------------------------------------------------------------------
// OMEGA v11 = byte-exact round-7 kernel (session best, 169.2 total) + ONE
// zero-risk addition: s_setprio(1) around the two MFMA clusters (phase-2
// conv, phase-6 DCN). Mechanism (T5, m191): 3-8 independent blocks/CU sit at
// DIFFERENT phases; boosting MFMA-executing waves lets them push through
// while other blocks' waves issue memory. Null on lockstep grids (m190) —
// our inter-block diversity is the attn-like case. All structure, LDS map,
// swizzle, barriers identical to r7 (every other knob falsified in r1-r10).
// LDS alias map (bytes in BIGB, 29376 B):
//   [0,29376)      phase 1-2: conv halo (204 rows x 72 shorts)
//   [0,12800)      phase 6:   S gather buffer (32 px x 200 shorts)
//   [12800,22016)  phase 3-4: Sg/Sb (2 x 32 x 72 shorts)
//   [12800,18560)  phase 5-6: coords (5 x 288 x 4 B)
//   [22016,25712)  phase 3-6: om_local (27 x 33 f32, written after halo dies)
// ---------------------------------------------------------------------------
#define CPITCH 72    // shorts per (srcrow, px) channel row in conv halo
#define SPITCH 200   // shorts per pixel row in gather buffer S
#define NPX 32       // pixels per block
#define FPX 72       // shorts per px row in Sg/Sb

__global__ __launch_bounds__(256) void k_omega(
    const float* __restrict__ x, const ushort* __restrict__ x_clh,
    const ushort* __restrict__ inter_clh,
    const float* __restrict__ b_off, const ushort* __restrict__ wfb,
    const ushort* __restrict__ wdT,
    const ushort* __restrict__ w1gb, const ushort* __restrict__ w1bb,
    const ushort* __restrict__ w2gb, const ushort* __restrict__ w2bb,
    const ushort* __restrict__ zp16, float* __restrict__ out) {
  __shared__ __align__(16) ushort BIGB[6 * 34 * CPITCH];   // 29376 B total LDS
  ushort* S  = BIGB;                      // 32*200 shorts = 12800 B (phases 1,6)
  ushort* Sg = BIGB + 6400;               // 32*72 shorts (phases 3-4)
  ushort* Sb = Sg + NPX * FPX;            // ends at short 11008 = byte 22016
  int*   cy  = (int*)(BIGB + 6400);       // coords (phases 5-6): 288 each
  int*   cx  = cy + 288;
  float* cwy = (float*)(cx + 288);
  float* cwx = cwy + 288;
  float* cm  = cwx + 288;                 // 5760 B total, ends byte 18560
  float* oml = (float*)(BIGB + 11008);    // om_local 27x33 f32 @ byte 22016

  int tid = threadIdx.x;
  int wave = tid >> 6, lane = tid & 63;
  int quad = lane >> 4, col = lane & 15;
  int rr = lane >> 3, g = lane & 7;
  // XCD-chunked swizzle (r7: FETCH -36%, kept).
  int bid = blockIdx.x;
  int wid = (bid & 7) * 256 + (bid >> 3);
  int pg0 = wid * NPX;
  int b = pg0 >> 14, hw0 = pg0 & 16383;
  int h = hw0 >> 7, w0 = hw0 & 127;
  int pt = wave >> 1, mt = wave & 1;
  int o_base = __builtin_amdgcn_readfirstlane(wave * 16);

  // ---- phase 1: conv halo staging ----
  {
    int ch = (tid & 7) * 8;
    unsigned bbase = (unsigned)b * HW;
#pragma unroll
    for (int it = 0; it < 7; ++it) {
      int e = it * 32 + (tid >> 3);
      if (e < 204) {
        int srcrow = e / 34, pxl = e % 34;
        int src = srcrow / 3, row = srcrow % 3;
        int hs = h + row - 1;
        int ps = w0 + pxl - 1;
        bool ok = ((unsigned)hs < 128u) && ((unsigned)ps < 128u);
        int hc = hs < 0 ? 0 : (hs > 127 ? 127 : hs);
        int pc = ps < 0 ? 0 : (ps > 127 ? 127 : ps);
        const ushort* sb = src ? inter_clh : x_clh;
        short8 v = *(const short8*)(sb + ((size_t)(bbase + (hc << 7) + pc)) * 64 + ch);
        short8 z = {0, 0, 0, 0, 0, 0, 0, 0};
        if (!ok) v = z;
        *(short8*)(&BIGB[e * CPITCH + ch]) = v;
      }
    }
  }
  __syncthreads();

  // ---- phase 2: conv MFMAs -> registers (setprio around MFMA cluster) ----
  f32x4 accx = {0.f, 0.f, 0.f, 0.f}, acci = {0.f, 0.f, 0.f, 0.f};
  {
    const ushort* wb0 = wfb + (size_t)(mt * 16 + col) * 128 + quad * 8;
    int pxb = pt * 16 + col;
    __builtin_amdgcn_s_setprio(1);
#pragma unroll
    for (int ky = 0; ky < 3; ++ky) {
#pragma unroll
      for (int kx = 0; kx < 3; ++kx) {
        int tap = ky * 3 + kx;
        const ushort* wt = wb0 + (size_t)tap * 4096;
#pragma unroll
        for (int ks = 0; ks < 2; ++ks) {
          short8 a0 = *(const short8*)(wt + ks * 32);
          short8 b0 = *(const short8*)(&BIGB[(ky * 34 + pxb + kx) * CPITCH + ks * 32 + quad * 8]);
          accx = __builtin_amdgcn_mfma_f32_16x16x32_bf16(a0, b0, accx, 0, 0, 0);
          short8 a1 = *(const short8*)(wt + 64 + ks * 32);
          short8 b1 = *(const short8*)(&BIGB[((3 + ky) * 34 + pxb + kx) * CPITCH + ks * 32 + quad * 8]);
          acci = __builtin_amdgcn_mfma_f32_16x16x32_bf16(a1, b1, acci, 0, 0, 0);
        }
      }
    }
    __builtin_amdgcn_s_setprio(0);
  }
  __syncthreads();   // all waves done READING halo; BIGB free for aliases

  // oml store into BIGB tail (disjoint from Sg/Sb written in phase 3).
#pragma unroll
  for (int r = 0; r < 4; ++r) {
    int o = mt * 16 + quad * 4 + r;
    if (o < 27) oml[o * 33 + pt * 16 + col] = accx[r] + acci[r];
  }

  // ---- phase 3: SFT stage A -> Sg/Sb ----
  f32x4 ag[2], ab[2];
#pragma unroll
  for (int nt = 0; nt < 2; ++nt) {
    ag[nt] = (f32x4){0.f, 0.f, 0.f, 0.f};
    ab[nt] = (f32x4){0.f, 0.f, 0.f, 0.f};
  }
#pragma unroll
  for (int ks = 0; ks < 2; ++ks) {
    short8 a_g = *(const short8*)(w1gb + (size_t)(o_base + col) * 64 + ks * 32 + quad * 8);
    short8 a_b = *(const short8*)(w1bb + (size_t)(o_base + col) * 64 + ks * 32 + quad * 8);
#pragma unroll
    for (int nt = 0; nt < 2; ++nt) {
      short8 bf = *(const short8*)(inter_clh + (size_t)(pg0 + nt * 16 + col) * 64 + ks * 32 + quad * 8);
      ag[nt] = __builtin_amdgcn_mfma_f32_16x16x32_bf16(a_g, bf, ag[nt], 0, 0, 0);
      ab[nt] = __builtin_amdgcn_mfma_f32_16x16x32_bf16(a_b, bf, ab[nt], 0, 0, 0);
    }
  }
#pragma unroll
  for (int nt = 0; nt < 2; ++nt) {
    int px = nt * 16 + col;
    ushort pkg[4], pkb[4];
#pragma unroll
    for (int r = 0; r < 4; ++r) {
      float vg = ag[nt][r]; vg = vg >= 0.f ? vg : 0.1f * vg;
      float vb = ab[nt][r]; vb = vb >= 0.f ? vb : 0.1f * vb;
      pkg[r] = f2bf(vg); pkb[r] = f2bf(vb);
    }
    *(uint2*)(&Sg[px * FPX + o_base + quad * 4]) = *(uint2*)pkg;
    *(uint2*)(&Sb[px * FPX + o_base + quad * 4]) = *(uint2*)pkb;
  }
  __syncthreads();

  // ---- phase 4: SFT stage B -> gamma/beta in registers ----
  f32x4 gg[2], gb[2];
#pragma unroll
  for (int nt = 0; nt < 2; ++nt) {
    gg[nt] = (f32x4){0.f, 0.f, 0.f, 0.f};
    gb[nt] = (f32x4){0.f, 0.f, 0.f, 0.f};
  }
#pragma unroll
  for (int ks = 0; ks < 2; ++ks) {
    short8 a_g = *(const short8*)(w2gb + (size_t)(o_base + col) * 64 + ks * 32 + quad * 8);
    short8 a_b = *(const short8*)(w2bb + (size_t)(o_base + col) * 64 + ks * 32 + quad * 8);
#pragma unroll
    for (int nt = 0; nt < 2; ++nt) {
      short8 bgf = *(const short8*)(Sg + (nt * 16 + col) * FPX + ks * 32 + quad * 8);
      short8 bbf = *(const short8*)(Sb + (nt * 16 + col) * FPX + ks * 32 + quad * 8);
      gg[nt] = __builtin_amdgcn_mfma_f32_16x16x32_bf16(a_g, bgf, gg[nt], 0, 0, 0);
      gb[nt] = __builtin_amdgcn_mfma_f32_16x16x32_bf16(a_b, bbf, gb[nt], 0, 0, 0);
    }
  }
  // Prefetch epilogue x values (independent of everything below).
  float xv[2][4];
#pragma unroll
  for (int nt = 0; nt < 2; ++nt)
#pragma unroll
    for (int r = 0; r < 4; ++r) {
      int o = o_base + quad * 4 + r;
      xv[nt][r] = x[(size_t)(b * 64 + o) * HW + hw0 + nt * 16 + col];
    }
  __syncthreads();   // Sg/Sb dead; region becomes coords

  // ---- phase 5: coords once per (pixel, tap) from om_local ----
  for (int i = tid; i < 9 * NPX; i += 256) {
    int k = i >> 5, p = i & 31;
    float dy = oml[k * 33 + p] + b_off[k];
    float dx = oml[(9 + k) * 33 + p] + b_off[9 + k];
    float mz = oml[(18 + k) * 33 + p] + b_off[18 + k];
    float py = (float)(h + (k / 3) - 1) + dy;
    float px = (float)(w0 + p + (k % 3) - 1) + dx;
    float y0f = floorf(py), x0f = floorf(px);
    cy[i] = (int)y0f;
    cx[i] = (int)x0f;
    cwy[i] = py - y0f;
    cwx[i] = px - x0f;
    cm[i] = 1.f / (1.f + __expf(-mz));
  }

  f32x4 acc[2];
  acc[0] = (f32x4){0.f, 0.f, 0.f, 0.f};
  acc[1] = (f32x4){0.f, 0.f, 0.f, 0.f};

  const ushort* bp = x_clh + (size_t)b * HW * 64;

  // ---- phase 6: gather + MFMA chunks ----
  for (int chunk = 0; chunk < 3; ++chunk) {
    __syncthreads();   // chunk 0: coords ready; later: S free for reuse
#pragma unroll
    for (int it = 0; it < 3; ++it) {
      int p = wave * 8 + rr;
      int idx = (chunk * 3 + it) * NPX + p;
      int y0 = cy[idx], x0 = cx[idx];
      float wy = cwy[idx], wx = cwx[idx], m = cm[idx];
      bool yok0 = (unsigned)y0 < 128u, yok1 = (unsigned)(y0 + 1) < 128u;
      bool xok0 = (unsigned)x0 < 128u, xok1 = (unsigned)(x0 + 1) < 128u;
      const ushort* r0 = bp + ((size_t)(int)((y0 << 7) + x0)) * 64 + g * 8;
      const ushort* r1 = r0 + (size_t)WW * 64;
      short8 s00 = *(const short8*)((yok0 && xok0) ? r0 : zp16);
      short8 s01 = *(const short8*)((yok0 && xok1) ? (r0 + 64) : zp16);
      short8 s10 = *(const short8*)((yok1 && xok0) ? r1 : zp16);
      short8 s11 = *(const short8*)((yok1 && xok1) ? (r1 + 64) : zp16);
      short8 outv;
#pragma unroll
      for (int j = 0; j < 8; ++j) {
        float v00 = bf2f((ushort)s00[j]), v01 = bf2f((ushort)s01[j]);
        float v10 = bf2f((ushort)s10[j]), v11 = bf2f((ushort)s11[j]);
        float top = v00 + (v01 - v00) * wx;
        float bot = v10 + (v11 - v10) * wx;
        float val = top + (bot - top) * wy;
        outv[j] = (short)f2bf(val * m);
      }
      *(short8*)(&S[p * SPITCH + it * 64 + g * 8]) = outv;
    }
    __syncthreads();
    const ushort* wrow = wdT + (size_t)(o_base + col) * 576 + chunk * 192 + quad * 8;
    const ushort* srow = S + quad * 8;
    __builtin_amdgcn_s_setprio(1);
#pragma unroll
    for (int ks = 0; ks < 6; ++ks) {
      short8 a = *(const short8*)(wrow + ks * 32);
#pragma unroll
      for (int nt = 0; nt < 2; ++nt) {
        short8 bf = *(const short8*)(srow + (nt * 16 + col) * SPITCH + ks * 32);
        acc[nt] = __builtin_amdgcn_mfma_f32_16x16x32_bf16(a, bf, acc[nt], 0, 0, 0);
      }
    }
    __builtin_amdgcn_s_setprio(0);
  }

  // ---- phase 7: epilogue: out = x + x*gamma + beta + dcn (single write) ----
#pragma unroll
  for (int nt = 0; nt < 2; ++nt) {
#pragma unroll
    for (int r = 0; r < 4; ++r) {
      int o = o_base + quad * 4 + r;
      size_t idx = (size_t)(b * 64 + o) * HW + hw0 + nt * 16 + col;
      out[idx] = xv[nt][r] + xv[nt][r] * gg[nt][r] + gb[nt][r] + acc[nt][r];
    }
  }
}

// ---------------------------------------------------------------------------
// Workspace plan (float slots), compacted ~17 MB (r4-verified):
//   x_clh     ushort [0        .. 2097152)
//   inter_clh ushort [2097152  .. 4194304)
//   wfb       ushort [4194304  .. 4212736)
//   wdT       ushort [4212736  .. 4231168)
//   w1gb/w1bb/w2gb/w2bb ushort 4 x 2048 float slots [4231168 .. 4239360)
//   zp        fp32   [4239360  .. 4239424)
// ---------------------------------------------------------------------------
extern "C" void kernel_launch(void* const* d_in, const int* in_sizes, int n_in,
                              void* d_out, int out_size, void* d_ws, size_t ws_size,
                              hipStream_t stream) {
  const float* x     = (const float*)d_in[0];
  const float* inter = (const float*)d_in[1];
  const float* w_off = (const float*)d_in[2];
  const float* b_off = (const float*)d_in[3];
  const float* w_dcn = (const float*)d_in[4];
  const float* wg1   = (const float*)d_in[5];
  const float* wg2   = (const float*)d_in[6];
  const float* wb1   = (const float*)d_in[7];
  const float* wb2   = (const float*)d_in[8];
  float* out = (float*)d_out;

  float* ws        = (float*)d_ws;
  ushort* x_clh    = (ushort*)ws;
  ushort* inter_clh= (ushort*)(ws + 2097152);
  ushort* wfb      = (ushort*)(ws + 4194304);
  ushort* wdT      = (ushort*)(ws + 4212736);
  ushort* w1gb     = (ushort*)(ws + 4231168);
  ushort* w1bb     = (ushort*)(ws + 4233216);
  ushort* w2gb     = (ushort*)(ws + 4235264);
  ushort* w2bb     = (ushort*)(ws + 4237312);
  float* zp        = ws + 4239360;

  // Prep: channels-last bf16 inputs + all packed weights + zero page.
  k_prep<<<1376, 256, 0, stream>>>(x, inter, w_off, w_dcn, wg1, wb1, wg2, wb2,
                                   x_clh, inter_clh, wfb, wdT,
                                   w1gb, w1bb, w2gb, w2bb, zp);

  // Fully fused conv + SFT + DCN (r7 structure + setprio on MFMA clusters).
  k_omega<<<2048, 256, 0, stream>>>(x, x_clh, inter_clh, b_off, wfb, wdT,
                                    w1gb, w1bb, w2gb, w2bb,
                                    (const ushort*)zp, out);
}

// Round 12
// 166.936 us; speedup vs baseline: 1.4393x; 1.0266x over previous
//
#include <hip/hip_runtime.h>
#include <hip/hip_bf16.h>
#include <math.h>

#define BB 4
#define CC 64
#define HH 128
#define WW 128
#define HW (HH*WW)          // 16384
#define NPIX (BB*HW)        // 65536

typedef __attribute__((ext_vector_type(8))) short short8;   // 8 bf16
typedef __attribute__((ext_vector_type(4))) float f32x4;

__device__ __forceinline__ float bf2f(ushort u) {
  union { unsigned u; float f; } v; v.u = ((unsigned)u) << 16; return v.f;
}
__device__ __forceinline__ ushort f2bf(float f) {
  __hip_bfloat16 h = __float2bfloat16(f); return *(ushort*)&h;
}

// ---------------------------------------------------------------------------
// Prep (verified, unchanged): NCHW fp32 -> channels-last bf16 + weights.
// ---------------------------------------------------------------------------
__global__ __launch_bounds__(256) void k_prep(
    const float* __restrict__ x, const float* __restrict__ inter,
    const float* __restrict__ w_off, const float* __restrict__ w_dcn,
    const float* __restrict__ wg1, const float* __restrict__ wb1,
    const float* __restrict__ wg2, const float* __restrict__ wb2,
    ushort* __restrict__ x_clh, ushort* __restrict__ inter_clh,
    ushort* __restrict__ wfb, ushort* __restrict__ wdT,
    ushort* __restrict__ w1gb, ushort* __restrict__ w1bb,
    ushort* __restrict__ w2gb, ushort* __restrict__ w2bb,
    float* __restrict__ zp) {
  __shared__ __align__(16) float tile[64 * 128];   // 32 KiB, xor-swizzled
  int blk = blockIdx.x;
  int tid = threadIdx.x;
  if (blk < 1024) {
    int sel = blk >> 9;
    int bh = blk & 511;
    int b = bh >> 7, h = bh & 127;
    const float* src = sel ? inter : x;
    ushort* dst = sel ? inter_clh : x_clh;
    const float* sp = src + (size_t)(b * 64) * HW + h * WW;
#pragma unroll
    for (int it = 0; it < 8; ++it) {
      int idx = it * 256 + tid;
      int c = idx >> 5, wq = idx & 31;
      float4 v = *(const float4*)(sp + (size_t)c * HW + wq * 4);
      int s = (c >> 3) & 7;
      *(float4*)(&tile[c * 128 + ((wq ^ s) << 2)]) = v;
    }
    __syncthreads();
    ushort* dp = dst + ((size_t)b * HW + h * WW) * 64;
#pragma unroll
    for (int it = 0; it < 4; ++it) {
      int idx = it * 256 + tid;
      int w = idx >> 3, c8 = idx & 7;
      short8 outv;
#pragma unroll
      for (int j = 0; j < 8; ++j) {
        int c = c8 * 8 + j;
        int sl = (w >> 2) ^ c8;
        float f = tile[c * 128 + (sl << 2) + (w & 3)];
        outv[j] = (short)f2bf(f);
      }
      *(short8*)(dp + (size_t)w * 64 + c8 * 8) = outv;
    }
  } else if (blk < 1168) {
    int i = (blk - 1024) * 256 + tid;
    if (i < 64) zp[i] = 0.f;
    if (i < 9 * 32 * 128) {
      int tap = i >> 12, rem = i & 4095, m = rem >> 7, c = rem & 127;
      float v = (m < 27) ? w_off[(size_t)(m * 128 + c) * 9 + tap] : 0.f;
      wfb[i] = f2bf(v);
    }
  } else if (blk < 1312) {
    int i = (blk - 1168) * 256 + tid;
    if (i < 64 * 64 * 9) {
      int o = i / 576, rem = i % 576, k = rem >> 6, c = rem & 63;
      wdT[i] = f2bf(w_dcn[(o * 64 + c) * 9 + k]);
    }
  } else {
    int i = (blk - 1312) * 256 + tid;   // 0..16383
    int m = i >> 12, j = i & 4095;
    const float* src = (m == 0) ? wg1 : (m == 1) ? wb1 : (m == 2) ? wg2 : wb2;
    ushort* dst = (m == 0) ? w1gb : (m == 1) ? w1bb : (m == 2) ? w2gb : w2bb;
    dst[j] = f2bf(src[j]);
  }
}

// ---------------------------------------------------------------------------
// OMEGA v12: stall-amortization. NPX=64 px/block, grid 1024 (4 blocks/CU of
// work), 11 barriers per block (vs r1's effective 16 per 64 px):
//   conv: v10 split-halo, halo width 66, 2 passes (4 barriers)
//   SFT:  A -> Sg/Sb -> B -> ev[4][4] (2 barriers, v4 ev-folding)
//   coords: 576 entries (1 barrier)
//   DCN: 2 px-halves, S holds the FULL 576-wide ch-tap axis for 32 px
//        -> gather, bar, 36 MFMA, bar (4 barriers total, was 12)
// All phase internals are verified r1/v10 lane mappings. Gather unroll 3
// (v6 lesson: don't batch 36 corner loads). No launch_bounds clamp
// (spill tripwire = WRITE_SIZE must stay 16384 KB).
// LDS alias map (48896 B total; serial reuse, barrier-separated):
//   [0,28512)      conv passes: halo 3 rows x 66 px x 72 shorts (x, then i)
//   [0,9216)       ph3-4: Sg 64px x 72 | [9216,18432): Sb
//   [18432,25560)  post-conv..ph5: oml 27 x 66 f32
//   [0,11520)      ph5-6: coords cy/cx/cwy/cwx/cm (5 x 576 x 4 B)
//   [11520,48896)  ph6: S 32 px x 584 shorts (overlays dead oml)
// ---------------------------------------------------------------------------
#define NPX 64
#define FPX 72       // Sg/Sb short pitch per pixel
#define SP2 584      // S short pitch per pixel (576 + 8 pad)

__global__ __launch_bounds__(256) void k_omega(
    const float* __restrict__ x, const ushort* __restrict__ x_clh,
    const ushort* __restrict__ inter_clh,
    const float* __restrict__ b_off, const ushort* __restrict__ wfb,
    const ushort* __restrict__ wdT,
    const ushort* __restrict__ w1gb, const ushort* __restrict__ w1bb,
    const ushort* __restrict__ w2gb, const ushort* __restrict__ w2bb,
    const ushort* __restrict__ zp16, float* __restrict__ out) {
  __shared__ __align__(16) ushort LDSB[24448];           // 48896 B
  ushort* halo = LDSB;                    // conv passes [0,28512)
  ushort* Sg = LDSB;                      // [0,9216)
  ushort* Sb = LDSB + 4608;               // [9216,18432)
  float* oml = (float*)(LDSB + 9216);     // byte 18432: 27 x 66 f32
  int*   cy  = (int*)LDSB;                // coords [0,11520)
  int*   cx  = cy + 576;
  float* cwy = (float*)(cx + 576);
  float* cwx = cwy + 576;
  float* cm  = cwx + 576;
  ushort* S  = LDSB + 5760;               // byte 11520: 32 x 584 shorts

  int tid = threadIdx.x;
  int wave = tid >> 6, lane = tid & 63;
  int quad = lane >> 4, col = lane & 15;
  int g = tid & 7;
  // XCD-chunked swizzle (bijective: 1024 = 8 x 128).
  int bid = blockIdx.x;
  int wid = (bid & 7) * 128 + (bid >> 3);
  int pg0 = wid * NPX;
  int b = pg0 >> 14, hw0 = pg0 & 16383;
  int h = hw0 >> 7, w0 = hw0 & 127;       // w0 in {0, 64}
  int pt = wave >> 1, mt = wave & 1;      // conv roles
  int o_base = __builtin_amdgcn_readfirstlane(wave * 16);  // SFT/DCN o-range

  // ---- conv: two split-halo passes (x, then inter), v10-verified ----
  f32x4 accx[2], acci[2];
  {
    int ch = (tid & 7) * 8;
    unsigned bbase = (unsigned)b * HW;
    const ushort* wb0 = wfb + (size_t)(mt * 16 + col) * 128 + quad * 8;
#pragma unroll 1
    for (int pass = 0; pass < 2; ++pass) {
      const ushort* sb = pass ? inter_clh : x_clh;
#pragma unroll
      for (int it = 0; it < 7; ++it) {
        int e = it * 32 + (tid >> 3);
        if (e < 198) {
          int row = e / 66, pxl = e % 66;
          int hs = h + row - 1;
          int ps = w0 + pxl - 1;
          bool ok = ((unsigned)hs < 128u) && ((unsigned)ps < 128u);
          int hc = hs < 0 ? 0 : (hs > 127 ? 127 : hs);
          int pc = ps < 0 ? 0 : (ps > 127 ? 127 : ps);
          short8 v = *(const short8*)(sb + ((size_t)(bbase + (hc << 7) + pc)) * 64 + ch);
          short8 z = {0, 0, 0, 0, 0, 0, 0, 0};
          if (!ok) v = z;
          *(short8*)(&halo[e * 72 + ch]) = v;
        }
      }
      __syncthreads();   // halo(pass) visible
      int aoff = pass ? 64 : 0;    // wfb c-slice: x=[0,64), inter=[64,128)
      f32x4 ap0 = {0.f, 0.f, 0.f, 0.f}, ap1 = {0.f, 0.f, 0.f, 0.f};
#pragma unroll
      for (int ky = 0; ky < 3; ++ky) {
#pragma unroll
        for (int kx = 0; kx < 3; ++kx) {
          const ushort* wt = wb0 + (size_t)(ky * 3 + kx) * 4096 + aoff;
#pragma unroll
          for (int ks = 0; ks < 2; ++ks) {
            short8 a = *(const short8*)(wt + ks * 32);
            short8 b0 = *(const short8*)(&halo[(ky * 66 + pt * 32 + col + kx) * 72 + ks * 32 + quad * 8]);
            ap0 = __builtin_amdgcn_mfma_f32_16x16x32_bf16(a, b0, ap0, 0, 0, 0);
            short8 b1 = *(const short8*)(&halo[(ky * 66 + pt * 32 + 16 + col + kx) * 72 + ks * 32 + quad * 8]);
            ap1 = __builtin_amdgcn_mfma_f32_16x16x32_bf16(a, b1, ap1, 0, 0, 0);
          }
        }
      }
      if (pass) { acci[0] = ap0; acci[1] = ap1; }
      else      { accx[0] = ap0; accx[1] = ap1; }
      __syncthreads();   // halo reads done; buffer free (restage / aliases)
    }
  }

  // oml write (halo dead; oml [18432,25560) now safe; readers wait at B2)
#pragma unroll
  for (int nt2 = 0; nt2 < 2; ++nt2)
#pragma unroll
    for (int r = 0; r < 4; ++r) {
      int o = mt * 16 + quad * 4 + r;
      if (o < 27) oml[o * 66 + pt * 32 + nt2 * 16 + col] = accx[nt2][r] + acci[nt2][r];
    }

  // ---- phase 3: SFT stage A (my 16 o x all 64 px) -> Sg/Sb ----
  f32x4 ag[4], ab[4];
#pragma unroll
  for (int nt = 0; nt < 4; ++nt) {
    ag[nt] = (f32x4){0.f, 0.f, 0.f, 0.f};
    ab[nt] = (f32x4){0.f, 0.f, 0.f, 0.f};
  }
#pragma unroll
  for (int ks = 0; ks < 2; ++ks) {
    short8 a_g = *(const short8*)(w1gb + (size_t)(o_base + col) * 64 + ks * 32 + quad * 8);
    short8 a_b = *(const short8*)(w1bb + (size_t)(o_base + col) * 64 + ks * 32 + quad * 8);
#pragma unroll
    for (int nt = 0; nt < 4; ++nt) {
      short8 bf = *(const short8*)(inter_clh + (size_t)(pg0 + nt * 16 + col) * 64 + ks * 32 + quad * 8);
      ag[nt] = __builtin_amdgcn_mfma_f32_16x16x32_bf16(a_g, bf, ag[nt], 0, 0, 0);
      ab[nt] = __builtin_amdgcn_mfma_f32_16x16x32_bf16(a_b, bf, ab[nt], 0, 0, 0);
    }
  }
#pragma unroll
  for (int nt = 0; nt < 4; ++nt) {
    int px = nt * 16 + col;
    ushort pkg[4], pkb[4];
#pragma unroll
    for (int r = 0; r < 4; ++r) {
      float vg = ag[nt][r]; vg = vg >= 0.f ? vg : 0.1f * vg;
      float vb = ab[nt][r]; vb = vb >= 0.f ? vb : 0.1f * vb;
      pkg[r] = f2bf(vg); pkb[r] = f2bf(vb);
    }
    *(uint2*)(&Sg[px * FPX + o_base + quad * 4]) = *(uint2*)pkg;
    *(uint2*)(&Sb[px * FPX + o_base + quad * 4]) = *(uint2*)pkb;
  }
  __syncthreads();   // B2: oml + Sg/Sb visible

  // ---- phase 4: SFT stage B -> ev[4][4] = x + x*gamma + beta ----
  f32x4 gg[4], gb[4];
#pragma unroll
  for (int nt = 0; nt < 4; ++nt) {
    gg[nt] = (f32x4){0.f, 0.f, 0.f, 0.f};
    gb[nt] = (f32x4){0.f, 0.f, 0.f, 0.f};
  }
#pragma unroll
  for (int ks = 0; ks < 2; ++ks) {
    short8 a_g = *(const short8*)(w2gb + (size_t)(o_base + col) * 64 + ks * 32 + quad * 8);
    short8 a_b = *(const short8*)(w2bb + (size_t)(o_base + col) * 64 + ks * 32 + quad * 8);
#pragma unroll
    for (int nt = 0; nt < 4; ++nt) {
      short8 bgf = *(const short8*)(Sg + (nt * 16 + col) * FPX + ks * 32 + quad * 8);
      short8 bbf = *(const short8*)(Sb + (nt * 16 + col) * FPX + ks * 32 + quad * 8);
      gg[nt] = __builtin_amdgcn_mfma_f32_16x16x32_bf16(a_g, bgf, gg[nt], 0, 0, 0);
      gb[nt] = __builtin_amdgcn_mfma_f32_16x16x32_bf16(a_b, bbf, gb[nt], 0, 0, 0);
    }
  }
  float ev[4][4];
#pragma unroll
  for (int nt = 0; nt < 4; ++nt)
#pragma unroll
    for (int r = 0; r < 4; ++r) {
      int o = o_base + quad * 4 + r;
      float xv = x[(size_t)(b * 64 + o) * HW + hw0 + nt * 16 + col];
      ev[nt][r] = xv + xv * gg[nt][r] + gb[nt][r];
    }
  __syncthreads();   // B3: Sg/Sb dead -> region becomes coords

  // ---- phase 5: coords (9 taps x 64 px) from oml ----
  for (int i = tid; i < 9 * NPX; i += 256) {
    int t = i >> 6, p = i & 63;
    float dy = oml[t * 66 + p] + b_off[t];
    float dx = oml[(9 + t) * 66 + p] + b_off[9 + t];
    float mz = oml[(18 + t) * 66 + p] + b_off[18 + t];
    float py = (float)(h + (t / 3) - 1) + dy;
    float px = (float)(w0 + p + (t % 3) - 1) + dx;
    float y0f = floorf(py), x0f = floorf(px);
    cy[i] = (int)y0f;
    cx[i] = (int)x0f;
    cwy[i] = py - y0f;
    cwx[i] = px - x0f;
    cm[i] = 1.f / (1.f + __expf(-mz));
  }
  __syncthreads();   // B4: coords ready; oml dead (S may overlay)

  // ---- phase 6: DCN in 2 px-halves; S holds full 576 ch-tap per px ----
  f32x4 acc[4];
#pragma unroll
  for (int nt = 0; nt < 4; ++nt) acc[nt] = (f32x4){0.f, 0.f, 0.f, 0.f};

  const ushort* bp = x_clh + (size_t)b * HW * 64;
  int p = tid >> 3;   // 0..31: pixel within half

#pragma unroll 1
  for (int half = 0; half < 2; ++half) {
    if (half) __syncthreads();   // S free (prev MFMA reads done)
#pragma unroll 3
    for (int t = 0; t < 9; ++t) {
      int idx = t * 64 + half * 32 + p;
      int y0 = cy[idx], x0 = cx[idx];
      float wy = cwy[idx], wx = cwx[idx], m = cm[idx];
      bool yok0 = (unsigned)y0 < 128u, yok1 = (unsigned)(y0 + 1) < 128u;
      bool xok0 = (unsigned)x0 < 128u, xok1 = (unsigned)(x0 + 1) < 128u;
      const ushort* r0 = bp + ((size_t)(int)((y0 << 7) + x0)) * 64 + g * 8;
      const ushort* r1 = r0 + (size_t)WW * 64;
      short8 s00 = *(const short8*)((yok0 && xok0) ? r0 : zp16);
      short8 s01 = *(const short8*)((yok0 && xok1) ? (r0 + 64) : zp16);
      short8 s10 = *(const short8*)((yok1 && xok0) ? r1 : zp16);
      short8 s11 = *(const short8*)((yok1 && xok1) ? (r1 + 64) : zp16);
      short8 outv;
#pragma unroll
      for (int j = 0; j < 8; ++j) {
        float v00 = bf2f((ushort)s00[j]), v01 = bf2f((ushort)s01[j]);
        float v10 = bf2f((ushort)s10[j]), v11 = bf2f((ushort)s11[j]);
        float top = v00 + (v01 - v00) * wx;
        float bot = v10 + (v11 - v10) * wx;
        float val = top + (bot - top) * wy;
        outv[j] = (short)f2bf(val * m);
      }
      *(short8*)(&S[p * SP2 + t * 64 + g * 8]) = outv;
    }
    __syncthreads();   // S ready
    const ushort* wrow = wdT + (size_t)(o_base + col) * 576 + quad * 8;
    const ushort* srow = S + quad * 8;
#pragma unroll
    for (int ks = 0; ks < 18; ++ks) {
      short8 a = *(const short8*)(wrow + ks * 32);
#pragma unroll
      for (int ntl = 0; ntl < 2; ++ntl) {
        short8 bfv = *(const short8*)(srow + (ntl * 16 + col) * SP2 + ks * 32);
        acc[half * 2 + ntl] = __builtin_amdgcn_mfma_f32_16x16x32_bf16(a, bfv, acc[half * 2 + ntl], 0, 0, 0);
      }
    }
  }

  // ---- phase 7: epilogue: out = ev + dcn (single pure write) ----
#pragma unroll
  for (int nt = 0; nt < 4; ++nt)
#pragma unroll
    for (int r = 0; r < 4; ++r) {
      int o = o_base + quad * 4 + r;
      size_t idx = (size_t)(b * 64 + o) * HW + hw0 + nt * 16 + col;
      out[idx] = ev[nt][r] + acc[nt][r];
    }
}

// ---------------------------------------------------------------------------
// Workspace plan (float slots), compacted ~17 MB (r4-verified):
//   x_clh     ushort [0        .. 2097152)
//   inter_clh ushort [2097152  .. 4194304)
//   wfb       ushort [4194304  .. 4212736)
//   wdT       ushort [4212736  .. 4231168)
//   w1gb/w1bb/w2gb/w2bb ushort 4 x 2048 float slots [4231168 .. 4239360)
//   zp        fp32   [4239360  .. 4239424)
// ---------------------------------------------------------------------------
extern "C" void kernel_launch(void* const* d_in, const int* in_sizes, int n_in,
                              void* d_out, int out_size, void* d_ws, size_t ws_size,
                              hipStream_t stream) {
  const float* x     = (const float*)d_in[0];
  const float* inter = (const float*)d_in[1];
  const float* w_off = (const float*)d_in[2];
  const float* b_off = (const float*)d_in[3];
  const float* w_dcn = (const float*)d_in[4];
  const float* wg1   = (const float*)d_in[5];
  const float* wg2   = (const float*)d_in[6];
  const float* wb1   = (const float*)d_in[7];
  const float* wb2   = (const float*)d_in[8];
  float* out = (float*)d_out;

  float* ws        = (float*)d_ws;
  ushort* x_clh    = (ushort*)ws;
  ushort* inter_clh= (ushort*)(ws + 2097152);
  ushort* wfb      = (ushort*)(ws + 4194304);
  ushort* wdT      = (ushort*)(ws + 4212736);
  ushort* w1gb     = (ushort*)(ws + 4231168);
  ushort* w1bb     = (ushort*)(ws + 4233216);
  ushort* w2gb     = (ushort*)(ws + 4235264);
  ushort* w2bb     = (ushort*)(ws + 4237312);
  float* zp        = ws + 4239360;

  // Prep: channels-last bf16 inputs + all packed weights + zero page.
  k_prep<<<1376, 256, 0, stream>>>(x, inter, w_off, w_dcn, wg1, wb1, wg2, wb2,
                                   x_clh, inter_clh, wfb, wdT,
                                   w1gb, w1bb, w2gb, w2bb, zp);

  // Fully fused conv + SFT + DCN (v12: 64 px/block, 11-barrier amortized).
  k_omega<<<1024, 256, 0, stream>>>(x, x_clh, inter_clh, b_off, wfb, wdT,
                                    w1gb, w1bb, w2gb, w2bb,
                                    (const ushort*)zp, out);
}